// Round 1
// baseline (512.974 us; speedup 1.0000x reference)
//
#include <hip/hip_runtime.h>
#include <math.h>

#define NN 100000
#define MM 50000
#define EE 600000
#define DD 128

// --- degree + per-row edge counts (counts stored in `cnt`) ---
__global__ void deg_count_kernel(const int* __restrict__ row, const float* __restrict__ val,
                                 float* __restrict__ deg, int* __restrict__ cnt) {
    int e = blockIdx.x * 256 + threadIdx.x;
    if (e < EE) {
        int r = row[e];
        atomicAdd(&deg[r], val[e]);
        atomicAdd(&cnt[r], 1);
    }
}

__global__ void dis_kernel(const float* __restrict__ deg, float* __restrict__ dis) {
    int i = blockIdx.x * 256 + threadIdx.x;
    if (i < MM) dis[i] = rsqrtf(deg[i] + 1e-8f);
}

// --- exclusive prefix sum over cnt[0..MM) -> rowptr[0..MM] (single block) ---
__global__ void scan_kernel(const int* __restrict__ cnt, int* __restrict__ rowptr) {
    __shared__ int wsum[16];
    __shared__ int carry_s;
    int tid = threadIdx.x;
    int lane = tid & 63;
    int w = tid >> 6;
    if (tid == 0) carry_s = 0;
    __syncthreads();
    for (int base = 0; base < MM; base += 1024) {
        int i = base + tid;
        int v = (i < MM) ? cnt[i] : 0;
        int x = v;
        #pragma unroll
        for (int off = 1; off < 64; off <<= 1) {
            int t = __shfl_up(x, off, 64);
            if (lane >= off) x += t;
        }
        if (lane == 63) wsum[w] = x;
        __syncthreads();
        if (w == 0 && lane < 16) {
            int y = wsum[lane];
            #pragma unroll
            for (int off = 1; off < 16; off <<= 1) {
                int t = __shfl_up(y, off, 64);
                if (lane >= off) y += t;
            }
            wsum[lane] = y;  // inclusive scan of wave sums
        }
        __syncthreads();
        int waveoff = (w == 0) ? 0 : wsum[w - 1];
        int total = wsum[15];
        if (i < MM) rowptr[i] = carry_s + waveoff + x - v;  // exclusive
        __syncthreads();
        if (tid == 0) carry_s += total;
        __syncthreads();
    }
    if (tid == 0) rowptr[MM] = carry_s;
}

__global__ void copy_cursor_kernel(const int* __restrict__ rowptr, int* __restrict__ cursor) {
    int i = blockIdx.x * 256 + threadIdx.x;
    if (i < MM) cursor[i] = rowptr[i];
}

// --- bucket edges by row; fold in symmetric normalization ---
__global__ void scatter_kernel(const int* __restrict__ row, const int* __restrict__ col,
                               const float* __restrict__ val, const float* __restrict__ dis,
                               int* __restrict__ cursor, int* __restrict__ col_s,
                               float* __restrict__ val_s) {
    int e = blockIdx.x * 256 + threadIdx.x;
    if (e < EE) {
        int r = row[e], c = col[e];
        int pos = atomicAdd(&cursor[r], 1);
        col_s[pos] = c;
        val_s[pos] = val[e] * dis[r] * dis[c];
    }
}

// --- X0 = features[index]; also build inverse index map ---
__global__ void gather_kernel(const float* __restrict__ feat, const int* __restrict__ index,
                              float* __restrict__ X0, int* __restrict__ invidx) {
    int i = blockIdx.x;
    int idx = index[i];
    X0[(size_t)i * DD + threadIdx.x] = feat[(size_t)idx * DD + threadIdx.x];
    if (threadIdx.x == 0) invidx[idx] = i;
}

// --- one wave per row CSR SpMM: Y[r] = sum_j val_s[j] * X[col_s[j]] ---
__global__ void spmm_kernel(const int* __restrict__ rowptr, const int* __restrict__ col_s,
                            const float* __restrict__ val_s, const float* __restrict__ X,
                            float* __restrict__ Y) {
    int lane = threadIdx.x & 63;
    int r = blockIdx.x * 4 + (threadIdx.x >> 6);
    if (r >= MM) return;
    int s = rowptr[r], e = rowptr[r + 1];
    float2 acc = make_float2(0.f, 0.f);
    for (int j = s; j < e; ++j) {
        int c = col_s[j];
        float wv = val_s[j];
        float2 xv = ((const float2*)(X + (size_t)c * DD))[lane];
        acc.x = fmaf(wv, xv.x, acc.x);
        acc.y = fmaf(wv, xv.y, acc.y);
    }
    ((float2*)(Y + (size_t)r * DD))[lane] = acc;
}

// --- MLP head: thread per node, weights in LDS, register accumulators ---
__global__ __launch_bounds__(256) void mlp_kernel(
    const float* __restrict__ feat, const float* __restrict__ X3,
    const int* __restrict__ invidx,
    const float* __restrict__ W1, const float* __restrict__ b1,
    const float* __restrict__ W2, const float* __restrict__ b2,
    const float* __restrict__ W3, const float* __restrict__ b3,
    const float* __restrict__ W4, float* __restrict__ out) {
    __shared__ float W1s[128 * 64];
    __shared__ float W2s[64 * 32];
    __shared__ float W3s[32 * 21];
    __shared__ float W4s[21];
    __shared__ float b1s[64], b2s[32], b3s[21];
    int tid = threadIdx.x;
    for (int i = tid; i < 128 * 64; i += 256) W1s[i] = W1[i];
    for (int i = tid; i < 64 * 32; i += 256) W2s[i] = W2[i];
    for (int i = tid; i < 32 * 21; i += 256) W3s[i] = W3[i];
    if (tid < 21) W4s[tid] = W4[tid];
    if (tid < 64) b1s[tid] = b1[tid];
    if (tid < 32) b2s[tid] = b2[tid];
    if (tid < 21) b3s[tid] = b3[tid];
    __syncthreads();
    int n = blockIdx.x * 256 + tid;
    if (n >= NN) return;
    int p = invidx[n];
    const float* xr = (p >= 0) ? (X3 + (size_t)p * DD) : (feat + (size_t)n * DD);
    const float4* x4 = (const float4*)xr;

    float h1[64];
    #pragma unroll
    for (int j = 0; j < 64; ++j) h1[j] = b1s[j];
    for (int k4 = 0; k4 < 32; ++k4) {
        float4 xv = x4[k4];
        #pragma unroll
        for (int kk = 0; kk < 4; ++kk) {
            float xs = (kk == 0) ? xv.x : (kk == 1) ? xv.y : (kk == 2) ? xv.z : xv.w;
            const float* wr = &W1s[(k4 * 4 + kk) * 64];
            #pragma unroll
            for (int j = 0; j < 64; ++j) h1[j] = fmaf(xs, wr[j], h1[j]);
        }
    }
    #pragma unroll
    for (int j = 0; j < 64; ++j) h1[j] = (h1[j] > 0.f) ? h1[j] : 0.01f * h1[j];

    float h2[32];
    #pragma unroll
    for (int j = 0; j < 32; ++j) h2[j] = b2s[j];
    #pragma unroll
    for (int k = 0; k < 64; ++k) {
        float xs = h1[k];
        const float* wr = &W2s[k * 32];
        #pragma unroll
        for (int j = 0; j < 32; ++j) h2[j] = fmaf(xs, wr[j], h2[j]);
    }
    #pragma unroll
    for (int j = 0; j < 32; ++j) h2[j] = (h2[j] > 0.f) ? h2[j] : 0.01f * h2[j];

    float h3[21];
    #pragma unroll
    for (int j = 0; j < 21; ++j) h3[j] = b3s[j];
    #pragma unroll
    for (int k = 0; k < 32; ++k) {
        float xs = h2[k];
        const float* wr = &W3s[k * 21];
        #pragma unroll
        for (int j = 0; j < 21; ++j) h3[j] = fmaf(xs, wr[j], h3[j]);
    }
    float s = 0.f;
    #pragma unroll
    for (int k = 0; k < 21; ++k) {
        float v = (h3[k] > 0.f) ? h3[k] : 0.01f * h3[k];
        s = fmaf(v, W4s[k], s);
    }
    out[n] = 1.f / (1.f + expf(-s));
}

extern "C" void kernel_launch(void* const* d_in, const int* in_sizes, int n_in,
                              void* d_out, int out_size, void* d_ws, size_t ws_size,
                              hipStream_t stream) {
    const float* feat = (const float*)d_in[0];
    const int*   index = (const int*)d_in[1];
    const int*   erow = (const int*)d_in[2];
    const int*   ecol = (const int*)d_in[3];
    const float* evalp = (const float*)d_in[4];
    const float* W1 = (const float*)d_in[5];
    const float* b1 = (const float*)d_in[6];
    const float* W2 = (const float*)d_in[7];
    const float* b2 = (const float*)d_in[8];
    const float* W3 = (const float*)d_in[9];
    const float* b3 = (const float*)d_in[10];
    const float* W4 = (const float*)d_in[11];
    float* out = (float*)d_out;

    char* ws = (char*)d_ws;
    size_t off = 0;
    auto alloc = [&](size_t bytes) -> void* {
        void* p = ws + off;
        off += (bytes + 255) & ~(size_t)255;
        return p;
    };
    float* deg    = (float*)alloc((size_t)MM * 4);
    float* dis    = (float*)alloc((size_t)MM * 4);
    int*   rowptr = (int*)  alloc((size_t)(MM + 1) * 4);
    int*   cursor = (int*)  alloc((size_t)MM * 4);   // doubles as counts buffer
    int*   col_s  = (int*)  alloc((size_t)EE * 4);
    float* val_s  = (float*)alloc((size_t)EE * 4);
    int*   invidx = (int*)  alloc((size_t)NN * 4);
    float* Xa     = (float*)alloc((size_t)MM * DD * 4);
    float* Xb     = (float*)alloc((size_t)MM * DD * 4);

    hipMemsetAsync(deg, 0, (size_t)MM * 4, stream);
    hipMemsetAsync(cursor, 0, (size_t)MM * 4, stream);
    hipMemsetAsync(invidx, 0xFF, (size_t)NN * 4, stream);  // -1

    deg_count_kernel<<<(EE + 255) / 256, 256, 0, stream>>>(erow, evalp, deg, cursor);
    dis_kernel<<<(MM + 255) / 256, 256, 0, stream>>>(deg, dis);
    scan_kernel<<<1, 1024, 0, stream>>>(cursor, rowptr);
    copy_cursor_kernel<<<(MM + 255) / 256, 256, 0, stream>>>(rowptr, cursor);
    scatter_kernel<<<(EE + 255) / 256, 256, 0, stream>>>(erow, ecol, evalp, dis, cursor, col_s, val_s);
    gather_kernel<<<MM, DD, 0, stream>>>(feat, index, Xa, invidx);

    spmm_kernel<<<(MM + 3) / 4, 256, 0, stream>>>(rowptr, col_s, val_s, Xa, Xb);
    spmm_kernel<<<(MM + 3) / 4, 256, 0, stream>>>(rowptr, col_s, val_s, Xb, Xa);
    spmm_kernel<<<(MM + 3) / 4, 256, 0, stream>>>(rowptr, col_s, val_s, Xa, Xb);

    mlp_kernel<<<(NN + 255) / 256, 256, 0, stream>>>(feat, Xb, invidx,
                                                     W1, b1, W2, b2, W3, b3, W4, out);
}

// Round 2
// 403.513 us; speedup vs baseline: 1.2713x; 1.2713x over previous
//
#include <hip/hip_runtime.h>
#include <math.h>

#define NN 100000
#define MM 50000
#define EE 600000
#define DD 128
#define NB 196  // ceil(MM/256)

// --- degree (weighted) + per-row edge counts ---
__global__ void deg_count_kernel(const int* __restrict__ row, const float* __restrict__ val,
                                 float* __restrict__ deg, int* __restrict__ cnt) {
    int e = blockIdx.x * 256 + threadIdx.x;
    if (e < EE) {
        int r = row[e];
        atomicAdd(&deg[r], val[e]);
        atomicAdd(&cnt[r], 1);
    }
}

__global__ void dis_kernel(const float* __restrict__ deg, float* __restrict__ dis) {
    int i = blockIdx.x * 256 + threadIdx.x;
    if (i < MM) dis[i] = rsqrtf(deg[i] + 1e-8f);
}

__global__ void inv_kernel(const int* __restrict__ index, int* __restrict__ invidx) {
    int i = blockIdx.x * 256 + threadIdx.x;
    if (i < MM) invidx[index[i]] = i;
}

// --- hierarchical scan: A) per-block inclusive scan, B) scan block sums, C) combine ---
__global__ void scanA_kernel(const int* __restrict__ cnt, int* __restrict__ partial,
                             int* __restrict__ bsum) {
    __shared__ int ws[4];
    int tid = threadIdx.x, lane = tid & 63, w = tid >> 6;
    int i = blockIdx.x * 256 + tid;
    int v = (i < MM) ? cnt[i] : 0;
    int x = v;
    #pragma unroll
    for (int off = 1; off < 64; off <<= 1) {
        int t = __shfl_up(x, off, 64);
        if (lane >= off) x += t;
    }
    if (lane == 63) ws[w] = x;
    __syncthreads();
    int add = 0;
    for (int q = 0; q < w; ++q) add += ws[q];
    x += add;
    if (i < MM) partial[i] = x;
    if (tid == 255) bsum[blockIdx.x] = x;
}

__global__ void scanB_kernel(const int* __restrict__ bsum, int* __restrict__ boff) {
    int lane = threadIdx.x;  // 64 threads
    int carry = 0;
    for (int base = 0; base < NB; base += 64) {
        int v = (base + lane < NB) ? bsum[base + lane] : 0;
        int x = v;
        #pragma unroll
        for (int off = 1; off < 64; off <<= 1) {
            int t = __shfl_up(x, off, 64);
            if (lane >= off) x += t;
        }
        if (base + lane < NB) boff[base + lane] = carry + x - v;
        carry += __shfl(x, 63);
    }
}

__global__ void scanC_kernel(const int* __restrict__ partial, const int* __restrict__ cnt,
                             const int* __restrict__ boff, int* __restrict__ rowptr,
                             int* __restrict__ cursor) {
    int i = blockIdx.x * 256 + threadIdx.x;
    if (i < MM) {
        int rp = partial[i] - cnt[i] + boff[i >> 8];
        rowptr[i] = rp;
        cursor[i] = rp;
    }
    if (i == 0) rowptr[MM] = EE;
}

// --- bucket edges by row; fold in symmetric normalization; two col maps ---
__global__ void scatter_kernel(const int* __restrict__ row, const int* __restrict__ col,
                               const float* __restrict__ val, const float* __restrict__ dis,
                               const int* __restrict__ index,
                               int* __restrict__ cursor, int* __restrict__ col_s,
                               int* __restrict__ colf_s, float* __restrict__ val_s) {
    int e = blockIdx.x * 256 + threadIdx.x;
    if (e < EE) {
        int r = row[e], c = col[e];
        int pos = atomicAdd(&cursor[r], 1);
        col_s[pos] = c;               // X-space column (layers 2,3)
        colf_s[pos] = index[c];       // feature-space column (layer 1)
        val_s[pos] = val[e] * dis[r] * dis[c];
    }
}

// --- one wave per row CSR SpMM, shfl-broadcast cols, 4x unrolled gathers ---
__global__ __launch_bounds__(256) void spmm_kernel(
    const int* __restrict__ rowptr, const int* __restrict__ cols,
    const float* __restrict__ vals, const float* __restrict__ X,
    float* __restrict__ Y) {
    int lane = threadIdx.x & 63;
    int r = blockIdx.x * 4 + (threadIdx.x >> 6);
    if (r >= MM) return;
    int s = rowptr[r], e = rowptr[r + 1];
    const float2* __restrict__ X2 = (const float2*)X;
    float accx = 0.f, accy = 0.f;
    for (int base = s; base < e; base += 64) {
        int cnt = min(64, e - base);
        int c = 0; float v = 0.f;
        if (lane < cnt) { c = cols[base + lane]; v = vals[base + lane]; }
        int j = 0;
        for (; j + 4 <= cnt; j += 4) {
            int c0 = __shfl(c, j);     float v0 = __shfl(v, j);
            int c1 = __shfl(c, j + 1); float v1 = __shfl(v, j + 1);
            int c2 = __shfl(c, j + 2); float v2 = __shfl(v, j + 2);
            int c3 = __shfl(c, j + 3); float v3 = __shfl(v, j + 3);
            float2 x0 = X2[(size_t)c0 * 64 + lane];
            float2 x1 = X2[(size_t)c1 * 64 + lane];
            float2 x2 = X2[(size_t)c2 * 64 + lane];
            float2 x3 = X2[(size_t)c3 * 64 + lane];
            accx = fmaf(v0, x0.x, accx); accy = fmaf(v0, x0.y, accy);
            accx = fmaf(v1, x1.x, accx); accy = fmaf(v1, x1.y, accy);
            accx = fmaf(v2, x2.x, accx); accy = fmaf(v2, x2.y, accy);
            accx = fmaf(v3, x3.x, accx); accy = fmaf(v3, x3.y, accy);
        }
        for (; j < cnt; ++j) {
            int cc = __shfl(c, j); float vv = __shfl(v, j);
            float2 xv = X2[(size_t)cc * 64 + lane];
            accx = fmaf(vv, xv.x, accx); accy = fmaf(vv, xv.y, accy);
        }
    }
    float2 o; o.x = accx; o.y = accy;
    ((float2*)Y)[(size_t)r * 64 + lane] = o;
}

// --- MLP head: thread per node, weights via wave-uniform scalar loads ---
__global__ __launch_bounds__(256) void mlp_kernel(
    const float* __restrict__ feat, const float* __restrict__ X3,
    const int* __restrict__ invidx,
    const float* __restrict__ W1, const float* __restrict__ b1,
    const float* __restrict__ W2, const float* __restrict__ b2,
    const float* __restrict__ W3, const float* __restrict__ b3,
    const float* __restrict__ W4, float* __restrict__ out) {
    int n = blockIdx.x * 256 + threadIdx.x;
    if (n >= NN) return;
    int p = invidx[n];
    const float* xr = (p >= 0) ? (X3 + (size_t)p * DD) : (feat + (size_t)n * DD);
    const float4* x4 = (const float4*)xr;

    float h1[64];
    #pragma unroll
    for (int j = 0; j < 64; ++j) h1[j] = b1[j];
    for (int k4 = 0; k4 < 32; ++k4) {
        float4 xv = x4[k4];
        #pragma unroll
        for (int kk = 0; kk < 4; ++kk) {
            float xs = (kk == 0) ? xv.x : (kk == 1) ? xv.y : (kk == 2) ? xv.z : xv.w;
            const float* wr = &W1[(k4 * 4 + kk) * 64];
            #pragma unroll
            for (int j = 0; j < 64; ++j) h1[j] = fmaf(xs, wr[j], h1[j]);
        }
    }
    #pragma unroll
    for (int j = 0; j < 64; ++j) h1[j] = (h1[j] > 0.f) ? h1[j] : 0.01f * h1[j];

    float h2[32];
    #pragma unroll
    for (int j = 0; j < 32; ++j) h2[j] = b2[j];
    for (int k = 0; k < 64; ++k) {
        float xs = h1[k];
        const float* wr = &W2[k * 32];
        #pragma unroll
        for (int j = 0; j < 32; ++j) h2[j] = fmaf(xs, wr[j], h2[j]);
    }
    #pragma unroll
    for (int j = 0; j < 32; ++j) h2[j] = (h2[j] > 0.f) ? h2[j] : 0.01f * h2[j];

    float h3[21];
    #pragma unroll
    for (int j = 0; j < 21; ++j) h3[j] = b3[j];
    for (int k = 0; k < 32; ++k) {
        float xs = h2[k];
        const float* wr = &W3[k * 21];
        #pragma unroll
        for (int j = 0; j < 21; ++j) h3[j] = fmaf(xs, wr[j], h3[j]);
    }
    float s = 0.f;
    #pragma unroll
    for (int k = 0; k < 21; ++k) {
        float v = (h3[k] > 0.f) ? h3[k] : 0.01f * h3[k];
        s = fmaf(v, W4[k], s);
    }
    out[n] = 1.f / (1.f + expf(-s));
}

extern "C" void kernel_launch(void* const* d_in, const int* in_sizes, int n_in,
                              void* d_out, int out_size, void* d_ws, size_t ws_size,
                              hipStream_t stream) {
    const float* feat = (const float*)d_in[0];
    const int*   index = (const int*)d_in[1];
    const int*   erow = (const int*)d_in[2];
    const int*   ecol = (const int*)d_in[3];
    const float* evalp = (const float*)d_in[4];
    const float* W1 = (const float*)d_in[5];
    const float* b1 = (const float*)d_in[6];
    const float* W2 = (const float*)d_in[7];
    const float* b2 = (const float*)d_in[8];
    const float* W3 = (const float*)d_in[9];
    const float* b3 = (const float*)d_in[10];
    const float* W4 = (const float*)d_in[11];
    float* out = (float*)d_out;

    char* ws = (char*)d_ws;
    size_t off = 0;
    auto alloc = [&](size_t bytes) -> void* {
        void* p = ws + off;
        off += (bytes + 255) & ~(size_t)255;
        return p;
    };
    float* deg     = (float*)alloc((size_t)MM * 4);
    float* dis     = (float*)alloc((size_t)MM * 4);
    int*   rowptr  = (int*)  alloc((size_t)(MM + 1) * 4);
    int*   cnt     = (int*)  alloc((size_t)MM * 4);
    int*   cursor  = (int*)  alloc((size_t)MM * 4);
    int*   partial = (int*)  alloc((size_t)MM * 4);
    int*   bsum    = (int*)  alloc((size_t)NB * 4);
    int*   boff    = (int*)  alloc((size_t)NB * 4);
    int*   col_s   = (int*)  alloc((size_t)EE * 4);
    int*   colf_s  = (int*)  alloc((size_t)EE * 4);
    float* val_s   = (float*)alloc((size_t)EE * 4);
    int*   invidx  = (int*)  alloc((size_t)NN * 4);
    float* Xa      = (float*)alloc((size_t)MM * DD * 4);
    float* Xb      = (float*)alloc((size_t)MM * DD * 4);

    hipMemsetAsync(deg, 0, (size_t)MM * 4, stream);
    hipMemsetAsync(cnt, 0, (size_t)MM * 4, stream);
    hipMemsetAsync(invidx, 0xFF, (size_t)NN * 4, stream);  // -1

    deg_count_kernel<<<(EE + 255) / 256, 256, 0, stream>>>(erow, evalp, deg, cnt);
    dis_kernel<<<(MM + 255) / 256, 256, 0, stream>>>(deg, dis);
    inv_kernel<<<(MM + 255) / 256, 256, 0, stream>>>(index, invidx);
    scanA_kernel<<<NB, 256, 0, stream>>>(cnt, partial, bsum);
    scanB_kernel<<<1, 64, 0, stream>>>(bsum, boff);
    scanC_kernel<<<(MM + 255) / 256, 256, 0, stream>>>(partial, cnt, boff, rowptr, cursor);
    scatter_kernel<<<(EE + 255) / 256, 256, 0, stream>>>(erow, ecol, evalp, dis, index,
                                                         cursor, col_s, colf_s, val_s);

    // layer 1 gathers directly from features via colf_s (no gather copy)
    spmm_kernel<<<(MM + 3) / 4, 256, 0, stream>>>(rowptr, colf_s, val_s, feat, Xa);
    spmm_kernel<<<(MM + 3) / 4, 256, 0, stream>>>(rowptr, col_s, val_s, Xa, Xb);
    spmm_kernel<<<(MM + 3) / 4, 256, 0, stream>>>(rowptr, col_s, val_s, Xb, Xa);

    mlp_kernel<<<(NN + 255) / 256, 256, 0, stream>>>(feat, Xa, invidx,
                                                     W1, b1, W2, b2, W3, b3, W4, out);
}

// Round 3
// 398.104 us; speedup vs baseline: 1.2885x; 1.0136x over previous
//
#include <hip/hip_runtime.h>
#include <math.h>

#define NN 100000
#define MM 50000
#define EE 600000
#define DD 128
#define NB 196  // ceil(MM/256)

// --- degree (weighted) + per-row edge counts ---
__global__ void deg_count_kernel(const int* __restrict__ row, const float* __restrict__ val,
                                 float* __restrict__ deg, int* __restrict__ cnt) {
    int e = blockIdx.x * 256 + threadIdx.x;
    if (e < EE) {
        int r = row[e];
        atomicAdd(&deg[r], val[e]);
        atomicAdd(&cnt[r], 1);
    }
}

__global__ void dis_kernel(const float* __restrict__ deg, float* __restrict__ dis) {
    int i = blockIdx.x * 256 + threadIdx.x;
    if (i < MM) dis[i] = rsqrtf(deg[i] + 1e-8f);
}

__global__ void inv_kernel(const int* __restrict__ index, int* __restrict__ invidx) {
    int i = blockIdx.x * 256 + threadIdx.x;
    if (i < MM) invidx[index[i]] = i;
}

// --- hierarchical scan ---
__global__ void scanA_kernel(const int* __restrict__ cnt, int* __restrict__ partial,
                             int* __restrict__ bsum) {
    __shared__ int ws[4];
    int tid = threadIdx.x, lane = tid & 63, w = tid >> 6;
    int i = blockIdx.x * 256 + tid;
    int v = (i < MM) ? cnt[i] : 0;
    int x = v;
    #pragma unroll
    for (int off = 1; off < 64; off <<= 1) {
        int t = __shfl_up(x, off, 64);
        if (lane >= off) x += t;
    }
    if (lane == 63) ws[w] = x;
    __syncthreads();
    int add = 0;
    for (int q = 0; q < w; ++q) add += ws[q];
    x += add;
    if (i < MM) partial[i] = x;
    if (tid == 255) bsum[blockIdx.x] = x;
}

__global__ void scanB_kernel(const int* __restrict__ bsum, int* __restrict__ boff) {
    int lane = threadIdx.x;  // 64 threads
    int carry = 0;
    for (int base = 0; base < NB; base += 64) {
        int v = (base + lane < NB) ? bsum[base + lane] : 0;
        int x = v;
        #pragma unroll
        for (int off = 1; off < 64; off <<= 1) {
            int t = __shfl_up(x, off, 64);
            if (lane >= off) x += t;
        }
        if (base + lane < NB) boff[base + lane] = carry + x - v;
        carry += __shfl(x, 63);
    }
}

__global__ void scanC_kernel(const int* __restrict__ partial, const int* __restrict__ cnt,
                             const int* __restrict__ boff, int* __restrict__ rowptr,
                             int* __restrict__ cursor) {
    int i = blockIdx.x * 256 + threadIdx.x;
    if (i < MM) {
        int rp = partial[i] - cnt[i] + boff[i >> 8];
        rowptr[i] = rp;
        cursor[i] = rp;
    }
    if (i == 0) rowptr[MM] = EE;
}

// --- bucket edges by row; fold in symmetric normalization; two col maps ---
__global__ void scatter_kernel(const int* __restrict__ row, const int* __restrict__ col,
                               const float* __restrict__ val, const float* __restrict__ dis,
                               const int* __restrict__ index,
                               int* __restrict__ cursor, int* __restrict__ col_s,
                               int* __restrict__ colf_s, float* __restrict__ val_s) {
    int e = blockIdx.x * 256 + threadIdx.x;
    if (e < EE) {
        int r = row[e], c = col[e];
        int pos = atomicAdd(&cursor[r], 1);
        col_s[pos] = c;
        colf_s[pos] = index[c];
        val_s[pos] = val[e] * dis[r] * dis[c];
    }
}

// --- one wave per row CSR SpMM, shfl-broadcast cols, 8x unrolled gathers ---
__global__ __launch_bounds__(256) void spmm_kernel(
    const int* __restrict__ rowptr, const int* __restrict__ cols,
    const float* __restrict__ vals, const float* __restrict__ X,
    float* __restrict__ Y) {
    int lane = threadIdx.x & 63;
    int r = blockIdx.x * 4 + (threadIdx.x >> 6);
    if (r >= MM) return;
    int s = rowptr[r], e = rowptr[r + 1];
    const float2* __restrict__ X2 = (const float2*)X;
    float accx = 0.f, accy = 0.f;
    for (int base = s; base < e; base += 64) {
        int cnt = min(64, e - base);
        int c = 0; float v = 0.f;
        if (lane < cnt) { c = cols[base + lane]; v = vals[base + lane]; }
        int j = 0;
        for (; j + 8 <= cnt; j += 8) {
            int c0 = __shfl(c, j);     float v0 = __shfl(v, j);
            int c1 = __shfl(c, j + 1); float v1 = __shfl(v, j + 1);
            int c2 = __shfl(c, j + 2); float v2 = __shfl(v, j + 2);
            int c3 = __shfl(c, j + 3); float v3 = __shfl(v, j + 3);
            int c4 = __shfl(c, j + 4); float v4 = __shfl(v, j + 4);
            int c5 = __shfl(c, j + 5); float v5 = __shfl(v, j + 5);
            int c6 = __shfl(c, j + 6); float v6 = __shfl(v, j + 6);
            int c7 = __shfl(c, j + 7); float v7 = __shfl(v, j + 7);
            float2 x0 = X2[(size_t)c0 * 64 + lane];
            float2 x1 = X2[(size_t)c1 * 64 + lane];
            float2 x2 = X2[(size_t)c2 * 64 + lane];
            float2 x3 = X2[(size_t)c3 * 64 + lane];
            float2 x4 = X2[(size_t)c4 * 64 + lane];
            float2 x5 = X2[(size_t)c5 * 64 + lane];
            float2 x6 = X2[(size_t)c6 * 64 + lane];
            float2 x7 = X2[(size_t)c7 * 64 + lane];
            accx = fmaf(v0, x0.x, accx); accy = fmaf(v0, x0.y, accy);
            accx = fmaf(v1, x1.x, accx); accy = fmaf(v1, x1.y, accy);
            accx = fmaf(v2, x2.x, accx); accy = fmaf(v2, x2.y, accy);
            accx = fmaf(v3, x3.x, accx); accy = fmaf(v3, x3.y, accy);
            accx = fmaf(v4, x4.x, accx); accy = fmaf(v4, x4.y, accy);
            accx = fmaf(v5, x5.x, accx); accy = fmaf(v5, x5.y, accy);
            accx = fmaf(v6, x6.x, accx); accy = fmaf(v6, x6.y, accy);
            accx = fmaf(v7, x7.x, accx); accy = fmaf(v7, x7.y, accy);
        }
        for (; j + 4 <= cnt; j += 4) {
            int c0 = __shfl(c, j);     float v0 = __shfl(v, j);
            int c1 = __shfl(c, j + 1); float v1 = __shfl(v, j + 1);
            int c2 = __shfl(c, j + 2); float v2 = __shfl(v, j + 2);
            int c3 = __shfl(c, j + 3); float v3 = __shfl(v, j + 3);
            float2 x0 = X2[(size_t)c0 * 64 + lane];
            float2 x1 = X2[(size_t)c1 * 64 + lane];
            float2 x2 = X2[(size_t)c2 * 64 + lane];
            float2 x3 = X2[(size_t)c3 * 64 + lane];
            accx = fmaf(v0, x0.x, accx); accy = fmaf(v0, x0.y, accy);
            accx = fmaf(v1, x1.x, accx); accy = fmaf(v1, x1.y, accy);
            accx = fmaf(v2, x2.x, accx); accy = fmaf(v2, x2.y, accy);
            accx = fmaf(v3, x3.x, accx); accy = fmaf(v3, x3.y, accy);
        }
        for (; j < cnt; ++j) {
            int cc = __shfl(c, j); float vv = __shfl(v, j);
            float2 xv = X2[(size_t)cc * 64 + lane];
            accx = fmaf(vv, xv.x, accx); accy = fmaf(vv, xv.y, accy);
        }
    }
    float2 o; o.x = accx; o.y = accy;
    ((float2*)Y)[(size_t)r * 64 + lane] = o;
}

// --- MLP head: 64 nodes/block, 128 threads, LDS-staged x, wave-uniform weights ---
#define NPB 64
#define XS 132   // x row stride in LDS (floats): 16B-aligned rows, bank-rotating
#define H1S 68
#define H2S 36

__global__ __launch_bounds__(128) void mlp_kernel(
    const float* __restrict__ feat, const float* __restrict__ X3,
    const int* __restrict__ invidx,
    const float* __restrict__ W1, const float* __restrict__ b1,
    const float* __restrict__ W2, const float* __restrict__ b2,
    const float* __restrict__ W3, const float* __restrict__ b3,
    const float* __restrict__ W4, float* __restrict__ out) {
    __shared__ float xs[NPB * XS];          // 33792 B; later overlaid: h1 [0..4352), h2 [4352..6656)
    __shared__ const float* sp[NPB];
    int tid = threadIdx.x;
    int nb = blockIdx.x * NPB;

    if (tid < NPB) {
        int n = nb + tid;
        const float* p = feat;  // dummy valid row for padding nodes
        if (n < NN) {
            int q = invidx[n];
            p = (q >= 0) ? (X3 + (size_t)q * DD) : (feat + (size_t)n * DD);
        }
        sp[tid] = p;
    }
    __syncthreads();

    // stage 64 rows x 512B, 4 rows per iteration (32 threads/row, float4)
    {
        int rsub = tid >> 5, c = tid & 31;
        #pragma unroll 4
        for (int g = 0; g < 16; ++g) {
            int row = g * 4 + rsub;
            const float4* s = (const float4*)sp[row];
            ((float4*)(xs + row * XS))[c] = s[c];
        }
    }
    __syncthreads();

    int lane = tid & 63;
    int jb = __builtin_amdgcn_readfirstlane((tid >> 6) * 32);  // wave-uniform output chunk

    // L1: h1[jb..jb+32) for node=lane
    float acc[32];
    #pragma unroll
    for (int j = 0; j < 32; ++j) acc[j] = b1[jb + j];
    {
        const float* xrow = xs + lane * XS;
        #pragma unroll 4
        for (int k = 0; k < 128; ++k) {
            float xk = xrow[k];
            const float* wr = W1 + k * 64 + jb;   // wave-uniform -> s_load
            #pragma unroll
            for (int j = 0; j < 32; ++j) acc[j] = fmaf(xk, wr[j], acc[j]);
        }
    }
    #pragma unroll
    for (int j = 0; j < 32; ++j) acc[j] = acc[j] > 0.f ? acc[j] : 0.01f * acc[j];
    __syncthreads();   // all waves done reading x before overlaying h1
    {
        float* h1p = xs + lane * H1S + jb;
        #pragma unroll
        for (int j4 = 0; j4 < 8; ++j4)
            ((float4*)h1p)[j4] = make_float4(acc[4*j4], acc[4*j4+1], acc[4*j4+2], acc[4*j4+3]);
    }
    __syncthreads();

    // L2: h2[jb2..jb2+16)
    int jb2 = __builtin_amdgcn_readfirstlane((tid >> 6) * 16);
    float a2[16];
    #pragma unroll
    for (int j = 0; j < 16; ++j) a2[j] = b2[jb2 + j];
    {
        const float* h1r = xs + lane * H1S;
        #pragma unroll 4
        for (int k = 0; k < 64; ++k) {
            float hk = h1r[k];
            const float* wr = W2 + k * 32 + jb2;
            #pragma unroll
            for (int j = 0; j < 16; ++j) a2[j] = fmaf(hk, wr[j], a2[j]);
        }
    }
    #pragma unroll
    for (int j = 0; j < 16; ++j) a2[j] = a2[j] > 0.f ? a2[j] : 0.01f * a2[j];
    {
        float* h2p = xs + NPB * H1S + lane * H2S + jb2;
        #pragma unroll
        for (int j4 = 0; j4 < 4; ++j4)
            ((float4*)h2p)[j4] = make_float4(a2[4*j4], a2[4*j4+1], a2[4*j4+2], a2[4*j4+3]);
    }
    __syncthreads();

    // L3 + L4: one thread per node (wave 0 only), h2 from LDS
    if (tid < NPB) {
        float a3[21];
        #pragma unroll
        for (int j = 0; j < 21; ++j) a3[j] = b3[j];
        const float* h2r = xs + NPB * H1S + tid * H2S;
        #pragma unroll 2
        for (int k = 0; k < 32; ++k) {
            float hk = h2r[k];
            const float* wr = W3 + k * 21;
            #pragma unroll
            for (int j = 0; j < 21; ++j) a3[j] = fmaf(hk, wr[j], a3[j]);
        }
        float s = 0.f;
        #pragma unroll
        for (int k = 0; k < 21; ++k) {
            float v = a3[k] > 0.f ? a3[k] : 0.01f * a3[k];
            s = fmaf(v, W4[k], s);
        }
        int n = nb + tid;
        if (n < NN) out[n] = 1.f / (1.f + expf(-s));
    }
}

extern "C" void kernel_launch(void* const* d_in, const int* in_sizes, int n_in,
                              void* d_out, int out_size, void* d_ws, size_t ws_size,
                              hipStream_t stream) {
    const float* feat = (const float*)d_in[0];
    const int*   index = (const int*)d_in[1];
    const int*   erow = (const int*)d_in[2];
    const int*   ecol = (const int*)d_in[3];
    const float* evalp = (const float*)d_in[4];
    const float* W1 = (const float*)d_in[5];
    const float* b1 = (const float*)d_in[6];
    const float* W2 = (const float*)d_in[7];
    const float* b2 = (const float*)d_in[8];
    const float* W3 = (const float*)d_in[9];
    const float* b3 = (const float*)d_in[10];
    const float* W4 = (const float*)d_in[11];
    float* out = (float*)d_out;

    char* ws = (char*)d_ws;
    size_t off = 0;
    auto alloc = [&](size_t bytes) -> void* {
        void* p = ws + off;
        off += (bytes + 255) & ~(size_t)255;
        return p;
    };
    float* deg     = (float*)alloc((size_t)MM * 4);
    float* dis     = (float*)alloc((size_t)MM * 4);
    int*   rowptr  = (int*)  alloc((size_t)(MM + 1) * 4);
    int*   cnt     = (int*)  alloc((size_t)MM * 4);
    int*   cursor  = (int*)  alloc((size_t)MM * 4);
    int*   partial = (int*)  alloc((size_t)MM * 4);
    int*   bsum    = (int*)  alloc((size_t)NB * 4);
    int*   boff    = (int*)  alloc((size_t)NB * 4);
    int*   col_s   = (int*)  alloc((size_t)EE * 4);
    int*   colf_s  = (int*)  alloc((size_t)EE * 4);
    float* val_s   = (float*)alloc((size_t)EE * 4);
    int*   invidx  = (int*)  alloc((size_t)NN * 4);
    float* Xa      = (float*)alloc((size_t)MM * DD * 4);
    float* Xb      = (float*)alloc((size_t)MM * DD * 4);

    hipMemsetAsync(deg, 0, (size_t)MM * 4, stream);
    hipMemsetAsync(cnt, 0, (size_t)MM * 4, stream);
    hipMemsetAsync(invidx, 0xFF, (size_t)NN * 4, stream);  // -1

    deg_count_kernel<<<(EE + 255) / 256, 256, 0, stream>>>(erow, evalp, deg, cnt);
    dis_kernel<<<(MM + 255) / 256, 256, 0, stream>>>(deg, dis);
    inv_kernel<<<(MM + 255) / 256, 256, 0, stream>>>(index, invidx);
    scanA_kernel<<<NB, 256, 0, stream>>>(cnt, partial, bsum);
    scanB_kernel<<<1, 64, 0, stream>>>(bsum, boff);
    scanC_kernel<<<(MM + 255) / 256, 256, 0, stream>>>(partial, cnt, boff, rowptr, cursor);
    scatter_kernel<<<(EE + 255) / 256, 256, 0, stream>>>(erow, ecol, evalp, dis, index,
                                                         cursor, col_s, colf_s, val_s);

    spmm_kernel<<<(MM + 3) / 4, 256, 0, stream>>>(rowptr, colf_s, val_s, feat, Xa);
    spmm_kernel<<<(MM + 3) / 4, 256, 0, stream>>>(rowptr, col_s, val_s, Xa, Xb);
    spmm_kernel<<<(MM + 3) / 4, 256, 0, stream>>>(rowptr, col_s, val_s, Xb, Xa);

    mlp_kernel<<<(NN + NPB - 1) / NPB, 128, 0, stream>>>(feat, Xa, invidx,
                                                         W1, b1, W2, b2, W3, b3, W4, out);
}

// Round 4
// 395.488 us; speedup vs baseline: 1.2971x; 1.0066x over previous
//
#include <hip/hip_runtime.h>
#include <math.h>

#define NN 100000
#define MM 50000
#define EE 600000
#define DD 128
#define NB 196  // ceil(MM/256)

// --- degree (weighted) + per-row edge counts ---
__global__ void deg_count_kernel(const int* __restrict__ row, const float* __restrict__ val,
                                 float* __restrict__ deg, int* __restrict__ cnt) {
    int e = blockIdx.x * 256 + threadIdx.x;
    if (e < EE) {
        int r = row[e];
        atomicAdd(&deg[r], val[e]);
        atomicAdd(&cnt[r], 1);
    }
}

// --- fused: dis = rsqrt(deg+eps); invidx[index[i]] = i; scanA over cnt ---
__global__ void fused_setup_kernel(const float* __restrict__ deg, float* __restrict__ dis,
                                   const int* __restrict__ index, int* __restrict__ invidx,
                                   const int* __restrict__ cnt, int* __restrict__ partial,
                                   int* __restrict__ bsum) {
    __shared__ int ws[4];
    int tid = threadIdx.x, lane = tid & 63, w = tid >> 6;
    int i = blockIdx.x * 256 + tid;
    if (i < MM) {
        dis[i] = rsqrtf(deg[i] + 1e-8f);
        invidx[index[i]] = i;
    }
    int v = (i < MM) ? cnt[i] : 0;
    int x = v;
    #pragma unroll
    for (int off = 1; off < 64; off <<= 1) {
        int t = __shfl_up(x, off, 64);
        if (lane >= off) x += t;
    }
    if (lane == 63) ws[w] = x;
    __syncthreads();
    int add = 0;
    for (int q = 0; q < w; ++q) add += ws[q];
    x += add;
    if (i < MM) partial[i] = x;
    if (tid == 255) bsum[blockIdx.x] = x;
}

__global__ void scanB_kernel(const int* __restrict__ bsum, int* __restrict__ boff) {
    int lane = threadIdx.x;  // 64 threads
    int carry = 0;
    for (int base = 0; base < NB; base += 64) {
        int v = (base + lane < NB) ? bsum[base + lane] : 0;
        int x = v;
        #pragma unroll
        for (int off = 1; off < 64; off <<= 1) {
            int t = __shfl_up(x, off, 64);
            if (lane >= off) x += t;
        }
        if (base + lane < NB) boff[base + lane] = carry + x - v;
        carry += __shfl(x, 63);
    }
}

__global__ void scanC_kernel(const int* __restrict__ partial, const int* __restrict__ cnt,
                             const int* __restrict__ boff, int* __restrict__ rowptr,
                             int* __restrict__ cursor) {
    int i = blockIdx.x * 256 + threadIdx.x;
    if (i < MM) {
        int rp = partial[i] - cnt[i] + boff[i >> 8];
        rowptr[i] = rp;
        cursor[i] = rp;
    }
    if (i == 0) rowptr[MM] = EE;
}

// --- bucket edges by row; fold in symmetric normalization; two col maps ---
__global__ void scatter_kernel(const int* __restrict__ row, const int* __restrict__ col,
                               const float* __restrict__ val, const float* __restrict__ dis,
                               const int* __restrict__ index,
                               int* __restrict__ cursor, int* __restrict__ col_s,
                               int* __restrict__ colf_s, float* __restrict__ val_s) {
    int e = blockIdx.x * 256 + threadIdx.x;
    if (e < EE) {
        int r = row[e], c = col[e];
        int pos = atomicAdd(&cursor[r], 1);
        col_s[pos] = c;
        colf_s[pos] = index[c];
        val_s[pos] = val[e] * dis[r] * dis[c];
    }
}

// --- SpMM: 16-lane group per row, 4 groups/wave = 4 independent gather chains ---
__global__ __launch_bounds__(256) void spmm_kernel(
    const int* __restrict__ rowptr, const int* __restrict__ cols,
    const float* __restrict__ vals, const float* __restrict__ X,
    float* __restrict__ Y) {
    int lane = threadIdx.x & 63;
    int wid = threadIdx.x >> 6;
    int g = lane >> 4, sub = lane & 15;
    int r = blockIdx.x * 16 + wid * 4 + g;
    bool valid = (r < MM);
    int rc = valid ? r : (MM - 1);
    int s = rowptr[rc], e = rowptr[rc + 1];
    const float4* __restrict__ X4 = (const float4*)X;
    float4 a0 = make_float4(0.f, 0.f, 0.f, 0.f);
    float4 a1 = make_float4(0.f, 0.f, 0.f, 0.f);
    for (int base = s; base < e; base += 16) {
        int cnt = min(16, e - base);
        int c = 0; float v = 0.f;
        if (sub < cnt) { c = cols[base + sub]; v = vals[base + sub]; }
        int j = 0;
        for (; j + 4 <= cnt; j += 4) {
            int c0 = __shfl(c, g * 16 + j);     float v0 = __shfl(v, g * 16 + j);
            int c1 = __shfl(c, g * 16 + j + 1); float v1 = __shfl(v, g * 16 + j + 1);
            int c2 = __shfl(c, g * 16 + j + 2); float v2 = __shfl(v, g * 16 + j + 2);
            int c3 = __shfl(c, g * 16 + j + 3); float v3 = __shfl(v, g * 16 + j + 3);
            float4 x00 = X4[(size_t)c0 * 32 + sub], x01 = X4[(size_t)c0 * 32 + 16 + sub];
            float4 x10 = X4[(size_t)c1 * 32 + sub], x11 = X4[(size_t)c1 * 32 + 16 + sub];
            float4 x20 = X4[(size_t)c2 * 32 + sub], x21 = X4[(size_t)c2 * 32 + 16 + sub];
            float4 x30 = X4[(size_t)c3 * 32 + sub], x31 = X4[(size_t)c3 * 32 + 16 + sub];
            a0.x = fmaf(v0, x00.x, a0.x); a0.y = fmaf(v0, x00.y, a0.y);
            a0.z = fmaf(v0, x00.z, a0.z); a0.w = fmaf(v0, x00.w, a0.w);
            a1.x = fmaf(v0, x01.x, a1.x); a1.y = fmaf(v0, x01.y, a1.y);
            a1.z = fmaf(v0, x01.z, a1.z); a1.w = fmaf(v0, x01.w, a1.w);
            a0.x = fmaf(v1, x10.x, a0.x); a0.y = fmaf(v1, x10.y, a0.y);
            a0.z = fmaf(v1, x10.z, a0.z); a0.w = fmaf(v1, x10.w, a0.w);
            a1.x = fmaf(v1, x11.x, a1.x); a1.y = fmaf(v1, x11.y, a1.y);
            a1.z = fmaf(v1, x11.z, a1.z); a1.w = fmaf(v1, x11.w, a1.w);
            a0.x = fmaf(v2, x20.x, a0.x); a0.y = fmaf(v2, x20.y, a0.y);
            a0.z = fmaf(v2, x20.z, a0.z); a0.w = fmaf(v2, x20.w, a0.w);
            a1.x = fmaf(v2, x21.x, a1.x); a1.y = fmaf(v2, x21.y, a1.y);
            a1.z = fmaf(v2, x21.z, a1.z); a1.w = fmaf(v2, x21.w, a1.w);
            a0.x = fmaf(v3, x30.x, a0.x); a0.y = fmaf(v3, x30.y, a0.y);
            a0.z = fmaf(v3, x30.z, a0.z); a0.w = fmaf(v3, x30.w, a0.w);
            a1.x = fmaf(v3, x31.x, a1.x); a1.y = fmaf(v3, x31.y, a1.y);
            a1.z = fmaf(v3, x31.z, a1.z); a1.w = fmaf(v3, x31.w, a1.w);
        }
        for (; j < cnt; ++j) {
            int cc = __shfl(c, g * 16 + j); float vv = __shfl(v, g * 16 + j);
            float4 x0 = X4[(size_t)cc * 32 + sub], x1 = X4[(size_t)cc * 32 + 16 + sub];
            a0.x = fmaf(vv, x0.x, a0.x); a0.y = fmaf(vv, x0.y, a0.y);
            a0.z = fmaf(vv, x0.z, a0.z); a0.w = fmaf(vv, x0.w, a0.w);
            a1.x = fmaf(vv, x1.x, a1.x); a1.y = fmaf(vv, x1.y, a1.y);
            a1.z = fmaf(vv, x1.z, a1.z); a1.w = fmaf(vv, x1.w, a1.w);
        }
    }
    if (valid) {
        float4* Y4 = (float4*)Y;
        Y4[(size_t)r * 32 + sub] = a0;
        Y4[(size_t)r * 32 + 16 + sub] = a1;
    }
}

// --- MLP head: 64 nodes/block, 256 threads (4 waves), transposed-LDS x,
//     wave-uniform j-chunks so weights go through s_load ---
#define NPB 64
#define XT 66   // transposed row stride (floats): bank stride 2 -> 2-way (free)

__global__ __launch_bounds__(256) void mlp_kernel(
    const float* __restrict__ feat, const float* __restrict__ X3,
    const int* __restrict__ invidx,
    const float* __restrict__ W1, const float* __restrict__ b1,
    const float* __restrict__ W2, const float* __restrict__ b2,
    const float* __restrict__ W3, const float* __restrict__ b3,
    const float* __restrict__ W4, float* __restrict__ out) {
    __shared__ float xt[128 * XT];      // 33792 B; rows 0..63 reused for h1t, 64..95 for h2t
    __shared__ const float* sp[NPB];
    int tid = threadIdx.x;
    int nb = blockIdx.x * NPB;

    if (tid < NPB) {
        int n = nb + tid;
        const float* p = feat;  // dummy valid row for padding nodes
        if (n < NN) {
            int q = invidx[n];
            p = (q >= 0) ? (X3 + (size_t)q * DD) : (feat + (size_t)n * DD);
        }
        sp[tid] = p;
    }
    __syncthreads();

    // stage transposed: xt[k][node]; consecutive tid -> consecutive k (coalesced global)
    #pragma unroll 4
    for (int i = tid; i < NPB * 128; i += 256) {
        int node = i >> 7, k = i & 127;
        xt[k * XT + node] = sp[node][k];
    }
    __syncthreads();

    int lane = tid & 63;                                        // node
    int jb = __builtin_amdgcn_readfirstlane((tid >> 6) * 16);   // wave-uniform j-chunk

    // L1: h1[jb..jb+16) for node=lane
    float acc[16];
    #pragma unroll
    for (int j = 0; j < 16; ++j) acc[j] = b1[jb + j];
    #pragma unroll 4
    for (int k = 0; k < 128; ++k) {
        float xk = xt[k * XT + lane];
        const float* wr = W1 + k * 64 + jb;   // wave-uniform -> s_load
        #pragma unroll
        for (int j = 0; j < 16; ++j) acc[j] = fmaf(xk, wr[j], acc[j]);
    }
    #pragma unroll
    for (int j = 0; j < 16; ++j) acc[j] = acc[j] > 0.f ? acc[j] : 0.01f * acc[j];
    __syncthreads();   // all waves done reading xt
    #pragma unroll
    for (int j = 0; j < 16; ++j) xt[(jb + j) * XT + lane] = acc[j];   // h1t[k1][node]
    __syncthreads();

    // L2: h2[jb2..jb2+8)
    int jb2 = __builtin_amdgcn_readfirstlane((tid >> 6) * 8);
    float a2[8];
    #pragma unroll
    for (int j = 0; j < 8; ++j) a2[j] = b2[jb2 + j];
    #pragma unroll 4
    for (int k = 0; k < 64; ++k) {
        float hk = xt[k * XT + lane];
        const float* wr = W2 + k * 32 + jb2;
        #pragma unroll
        for (int j = 0; j < 8; ++j) a2[j] = fmaf(hk, wr[j], a2[j]);
    }
    #pragma unroll
    for (int j = 0; j < 8; ++j) a2[j] = a2[j] > 0.f ? a2[j] : 0.01f * a2[j];
    __syncthreads();
    #pragma unroll
    for (int j = 0; j < 8; ++j) xt[(64 + jb2 + j) * XT + lane] = a2[j];  // h2t
    __syncthreads();

    // L3 + L4: one thread per node (wave 0)
    if (tid < NPB) {
        float a3[21];
        #pragma unroll
        for (int j = 0; j < 21; ++j) a3[j] = b3[j];
        #pragma unroll 2
        for (int k = 0; k < 32; ++k) {
            float hk = xt[(64 + k) * XT + tid];
            const float* wr = W3 + k * 21;
            #pragma unroll
            for (int j = 0; j < 21; ++j) a3[j] = fmaf(hk, wr[j], a3[j]);
        }
        float s = 0.f;
        #pragma unroll
        for (int k = 0; k < 21; ++k) {
            float v = a3[k] > 0.f ? a3[k] : 0.01f * a3[k];
            s = fmaf(v, W4[k], s);
        }
        int n = nb + tid;
        if (n < NN) out[n] = 1.f / (1.f + expf(-s));
    }
}

extern "C" void kernel_launch(void* const* d_in, const int* in_sizes, int n_in,
                              void* d_out, int out_size, void* d_ws, size_t ws_size,
                              hipStream_t stream) {
    const float* feat = (const float*)d_in[0];
    const int*   index = (const int*)d_in[1];
    const int*   erow = (const int*)d_in[2];
    const int*   ecol = (const int*)d_in[3];
    const float* evalp = (const float*)d_in[4];
    const float* W1 = (const float*)d_in[5];
    const float* b1 = (const float*)d_in[6];
    const float* W2 = (const float*)d_in[7];
    const float* b2 = (const float*)d_in[8];
    const float* W3 = (const float*)d_in[9];
    const float* b3 = (const float*)d_in[10];
    const float* W4 = (const float*)d_in[11];
    float* out = (float*)d_out;

    char* ws = (char*)d_ws;
    size_t off = 0;
    auto alloc = [&](size_t bytes) -> void* {
        void* p = ws + off;
        off += (bytes + 255) & ~(size_t)255;
        return p;
    };
    float* deg     = (float*)alloc((size_t)MM * 4);
    float* dis     = (float*)alloc((size_t)MM * 4);
    int*   rowptr  = (int*)  alloc((size_t)(MM + 1) * 4);
    int*   cnt     = (int*)  alloc((size_t)MM * 4);
    int*   cursor  = (int*)  alloc((size_t)MM * 4);
    int*   partial = (int*)  alloc((size_t)MM * 4);
    int*   bsum    = (int*)  alloc((size_t)NB * 4);
    int*   boff    = (int*)  alloc((size_t)NB * 4);
    int*   col_s   = (int*)  alloc((size_t)EE * 4);
    int*   colf_s  = (int*)  alloc((size_t)EE * 4);
    float* val_s   = (float*)alloc((size_t)EE * 4);
    int*   invidx  = (int*)  alloc((size_t)NN * 4);
    float* Xa      = (float*)alloc((size_t)MM * DD * 4);
    float* Xb      = (float*)alloc((size_t)MM * DD * 4);

    hipMemsetAsync(deg, 0, (size_t)MM * 4, stream);
    hipMemsetAsync(cnt, 0, (size_t)MM * 4, stream);
    hipMemsetAsync(invidx, 0xFF, (size_t)NN * 4, stream);  // -1

    deg_count_kernel<<<(EE + 255) / 256, 256, 0, stream>>>(erow, evalp, deg, cnt);
    fused_setup_kernel<<<NB, 256, 0, stream>>>(deg, dis, index, invidx, cnt, partial, bsum);
    scanB_kernel<<<1, 64, 0, stream>>>(bsum, boff);
    scanC_kernel<<<(MM + 255) / 256, 256, 0, stream>>>(partial, cnt, boff, rowptr, cursor);
    scatter_kernel<<<(EE + 255) / 256, 256, 0, stream>>>(erow, ecol, evalp, dis, index,
                                                         cursor, col_s, colf_s, val_s);

    spmm_kernel<<<(MM + 15) / 16, 256, 0, stream>>>(rowptr, colf_s, val_s, feat, Xa);
    spmm_kernel<<<(MM + 15) / 16, 256, 0, stream>>>(rowptr, col_s, val_s, Xa, Xb);
    spmm_kernel<<<(MM + 15) / 16, 256, 0, stream>>>(rowptr, col_s, val_s, Xb, Xa);

    mlp_kernel<<<(NN + NPB - 1) / NPB, 256, 0, stream>>>(feat, Xa, invidx,
                                                         W1, b1, W2, b2, W3, b3, W4, out);
}

// Round 5
// 395.192 us; speedup vs baseline: 1.2980x; 1.0007x over previous
//
#include <hip/hip_runtime.h>
#include <math.h>

#define NN 100000
#define MM 50000
#define EE 600000
#define DD 128
#define NB 196  // ceil(MM/256)

// --- degree (weighted) + per-row edge counts + slot assignment + invidx init ---
__global__ void deg_count_kernel(const int* __restrict__ row, const float* __restrict__ val,
                                 float* __restrict__ deg, int* __restrict__ cnt,
                                 int* __restrict__ slot, int* __restrict__ invidx) {
    int e = blockIdx.x * 256 + threadIdx.x;
    if (e < NN) invidx[e] = -1;
    if (e < EE) {
        int r = row[e];
        atomicAdd(&deg[r], val[e]);
        slot[e] = atomicAdd(&cnt[r], 1);
    }
}

// --- fused: dis = rsqrt(deg+eps); invidx[index[i]] = i; scanA over cnt ---
__global__ void fused_setup_kernel(const float* __restrict__ deg, float* __restrict__ dis,
                                   const int* __restrict__ index, int* __restrict__ invidx,
                                   const int* __restrict__ cnt, int* __restrict__ partial,
                                   int* __restrict__ bsum) {
    __shared__ int ws[4];
    int tid = threadIdx.x, lane = tid & 63, w = tid >> 6;
    int i = blockIdx.x * 256 + tid;
    if (i < MM) {
        dis[i] = rsqrtf(deg[i] + 1e-8f);
        invidx[index[i]] = i;
    }
    int v = (i < MM) ? cnt[i] : 0;
    int x = v;
    #pragma unroll
    for (int off = 1; off < 64; off <<= 1) {
        int t = __shfl_up(x, off, 64);
        if (lane >= off) x += t;
    }
    if (lane == 63) ws[w] = x;
    __syncthreads();
    int add = 0;
    for (int q = 0; q < w; ++q) add += ws[q];
    x += add;
    if (i < MM) partial[i] = x;
    if (tid == 255) bsum[blockIdx.x] = x;
}

__global__ void scanB_kernel(const int* __restrict__ bsum, int* __restrict__ boff) {
    int lane = threadIdx.x;  // 64 threads
    int carry = 0;
    for (int base = 0; base < NB; base += 64) {
        int v = (base + lane < NB) ? bsum[base + lane] : 0;
        int x = v;
        #pragma unroll
        for (int off = 1; off < 64; off <<= 1) {
            int t = __shfl_up(x, off, 64);
            if (lane >= off) x += t;
        }
        if (base + lane < NB) boff[base + lane] = carry + x - v;
        carry += __shfl(x, 63);
    }
}

__global__ void scanC_kernel(const int* __restrict__ partial, const int* __restrict__ cnt,
                             const int* __restrict__ boff, int* __restrict__ rowptr) {
    int i = blockIdx.x * 256 + threadIdx.x;
    if (i < MM) rowptr[i] = partial[i] - cnt[i] + boff[i >> 8];
    if (i == 0) rowptr[MM] = EE;
}

// --- bucket edges by row (atomic-free: pos = rowptr[r] + slot[e]) ---
__global__ void scatter_kernel(const int* __restrict__ row, const int* __restrict__ col,
                               const float* __restrict__ val, const float* __restrict__ dis,
                               const int* __restrict__ index, const int* __restrict__ rowptr,
                               const int* __restrict__ slot, int* __restrict__ col_s,
                               int* __restrict__ colf_s, float* __restrict__ val_s) {
    int e = blockIdx.x * 256 + threadIdx.x;
    if (e < EE) {
        int r = row[e], c = col[e];
        int pos = rowptr[r] + slot[e];
        col_s[pos] = c;
        colf_s[pos] = index[c];
        val_s[pos] = val[e] * dis[r] * dis[c];
    }
}

// --- SpMM: 16-lane group per row, 4 groups/wave = 4 independent gather chains ---
__global__ __launch_bounds__(256) void spmm_kernel(
    const int* __restrict__ rowptr, const int* __restrict__ cols,
    const float* __restrict__ vals, const float* __restrict__ X,
    float* __restrict__ Y) {
    int lane = threadIdx.x & 63;
    int wid = threadIdx.x >> 6;
    int g = lane >> 4, sub = lane & 15;
    int r = blockIdx.x * 16 + wid * 4 + g;
    bool valid = (r < MM);
    int rc = valid ? r : (MM - 1);
    int s = rowptr[rc], e = rowptr[rc + 1];
    const float4* __restrict__ X4 = (const float4*)X;
    float4 a0 = make_float4(0.f, 0.f, 0.f, 0.f);
    float4 a1 = make_float4(0.f, 0.f, 0.f, 0.f);
    for (int base = s; base < e; base += 16) {
        int cnt = min(16, e - base);
        int c = 0; float v = 0.f;
        if (sub < cnt) { c = cols[base + sub]; v = vals[base + sub]; }
        int j = 0;
        for (; j + 4 <= cnt; j += 4) {
            int c0 = __shfl(c, g * 16 + j);     float v0 = __shfl(v, g * 16 + j);
            int c1 = __shfl(c, g * 16 + j + 1); float v1 = __shfl(v, g * 16 + j + 1);
            int c2 = __shfl(c, g * 16 + j + 2); float v2 = __shfl(v, g * 16 + j + 2);
            int c3 = __shfl(c, g * 16 + j + 3); float v3 = __shfl(v, g * 16 + j + 3);
            float4 x00 = X4[(size_t)c0 * 32 + sub], x01 = X4[(size_t)c0 * 32 + 16 + sub];
            float4 x10 = X4[(size_t)c1 * 32 + sub], x11 = X4[(size_t)c1 * 32 + 16 + sub];
            float4 x20 = X4[(size_t)c2 * 32 + sub], x21 = X4[(size_t)c2 * 32 + 16 + sub];
            float4 x30 = X4[(size_t)c3 * 32 + sub], x31 = X4[(size_t)c3 * 32 + 16 + sub];
            a0.x = fmaf(v0, x00.x, a0.x); a0.y = fmaf(v0, x00.y, a0.y);
            a0.z = fmaf(v0, x00.z, a0.z); a0.w = fmaf(v0, x00.w, a0.w);
            a1.x = fmaf(v0, x01.x, a1.x); a1.y = fmaf(v0, x01.y, a1.y);
            a1.z = fmaf(v0, x01.z, a1.z); a1.w = fmaf(v0, x01.w, a1.w);
            a0.x = fmaf(v1, x10.x, a0.x); a0.y = fmaf(v1, x10.y, a0.y);
            a0.z = fmaf(v1, x10.z, a0.z); a0.w = fmaf(v1, x10.w, a0.w);
            a1.x = fmaf(v1, x11.x, a1.x); a1.y = fmaf(v1, x11.y, a1.y);
            a1.z = fmaf(v1, x11.z, a1.z); a1.w = fmaf(v1, x11.w, a1.w);
            a0.x = fmaf(v2, x20.x, a0.x); a0.y = fmaf(v2, x20.y, a0.y);
            a0.z = fmaf(v2, x20.z, a0.z); a0.w = fmaf(v2, x20.w, a0.w);
            a1.x = fmaf(v2, x21.x, a1.x); a1.y = fmaf(v2, x21.y, a1.y);
            a1.z = fmaf(v2, x21.z, a1.z); a1.w = fmaf(v2, x21.w, a1.w);
            a0.x = fmaf(v3, x30.x, a0.x); a0.y = fmaf(v3, x30.y, a0.y);
            a0.z = fmaf(v3, x30.z, a0.z); a0.w = fmaf(v3, x30.w, a0.w);
            a1.x = fmaf(v3, x31.x, a1.x); a1.y = fmaf(v3, x31.y, a1.y);
            a1.z = fmaf(v3, x31.z, a1.z); a1.w = fmaf(v3, x31.w, a1.w);
        }
        for (; j < cnt; ++j) {
            int cc = __shfl(c, g * 16 + j); float vv = __shfl(v, g * 16 + j);
            float4 x0 = X4[(size_t)cc * 32 + sub], x1 = X4[(size_t)cc * 32 + 16 + sub];
            a0.x = fmaf(vv, x0.x, a0.x); a0.y = fmaf(vv, x0.y, a0.y);
            a0.z = fmaf(vv, x0.z, a0.z); a0.w = fmaf(vv, x0.w, a0.w);
            a1.x = fmaf(vv, x1.x, a1.x); a1.y = fmaf(vv, x1.y, a1.y);
            a1.z = fmaf(vv, x1.z, a1.z); a1.w = fmaf(vv, x1.w, a1.w);
        }
    }
    if (valid) {
        float4* Y4 = (float4*)Y;
        Y4[(size_t)r * 32 + sub] = a0;
        Y4[(size_t)r * 32 + 16 + sub] = a1;
    }
}

// --- MLP head: x LDS-staged then bulk-copied to REGISTERS (2 k-phases);
//     k-loop touches only s_load weights + fma (no ds/smem lgkm mixing).
//     XT=65: perfect bank rotation, conflict-free staging & copies. ---
#define NPB 64
#define XT 65

__global__ __launch_bounds__(256) void mlp_kernel(
    const float* __restrict__ feat, const float* __restrict__ X3,
    const int* __restrict__ invidx,
    const float* __restrict__ W1, const float* __restrict__ b1,
    const float* __restrict__ W2, const float* __restrict__ b2,
    const float* __restrict__ W3, const float* __restrict__ b3,
    const float* __restrict__ W4, float* __restrict__ out) {
    __shared__ float xt[128 * XT];      // 33280 B; [k][node]; rows 0..63 reused for h1t, 64..95 for h2t
    __shared__ const float* sp[NPB];
    int tid = threadIdx.x;
    int nb = blockIdx.x * NPB;

    if (tid < NPB) {
        int n = nb + tid;
        const float* p = feat;  // dummy valid row for padding nodes
        if (n < NN) {
            int q = invidx[n];
            p = (q >= 0) ? (X3 + (size_t)q * DD) : (feat + (size_t)n * DD);
        }
        sp[tid] = p;
    }
    __syncthreads();

    // stage transposed: xt[k][node]; wave reads 256B contiguous per inst; writes bank-rotated
    #pragma unroll
    for (int it = 0; it < 32; ++it) {
        int i = it * 256 + tid;
        int node = i >> 7, k = i & 127;
        xt[k * XT + node] = sp[node][k];
    }
    __syncthreads();

    int lane = tid & 63;                                        // node
    int w = tid >> 6;
    int jb = __builtin_amdgcn_readfirstlane(w * 16);            // wave-uniform j-chunk

    // L1: h1[jb..jb+16) for node=lane; x in registers, weights via s_load only
    float acc[16];
    #pragma unroll
    for (int j = 0; j < 16; ++j) acc[j] = b1[jb + j];

    float xk[64];
    #pragma unroll
    for (int k = 0; k < 64; ++k) xk[k] = xt[k * XT + lane];     // phase-1 bulk copy
    #pragma unroll
    for (int k = 0; k < 64; ++k) {
        const float* wr = W1 + k * 64 + jb;                     // wave-uniform -> s_load
        #pragma unroll
        for (int j = 0; j < 16; ++j) acc[j] = fmaf(xk[k], wr[j], acc[j]);
    }
    #pragma unroll
    for (int k = 0; k < 64; ++k) xk[k] = xt[(64 + k) * XT + lane];  // phase-2 bulk copy
    __syncthreads();   // all waves finished reading x region; xt rows 0..63 now reusable
    #pragma unroll
    for (int k = 0; k < 64; ++k) {
        const float* wr = W1 + (64 + k) * 64 + jb;
        #pragma unroll
        for (int j = 0; j < 16; ++j) acc[j] = fmaf(xk[k], wr[j], acc[j]);
    }
    #pragma unroll
    for (int j = 0; j < 16; ++j) acc[j] = acc[j] > 0.f ? acc[j] : 0.01f * acc[j];
    #pragma unroll
    for (int j = 0; j < 16; ++j) xt[(jb + j) * XT + lane] = acc[j];   // h1t[j][node]
    __syncthreads();

    // L2: h2[jb2..jb2+8); h1 bulk-copied to regs
    int jb2 = __builtin_amdgcn_readfirstlane(w * 8);
    float hk[64];
    #pragma unroll
    for (int k = 0; k < 64; ++k) hk[k] = xt[k * XT + lane];
    float a2[8];
    #pragma unroll
    for (int j = 0; j < 8; ++j) a2[j] = b2[jb2 + j];
    #pragma unroll
    for (int k = 0; k < 64; ++k) {
        const float* wr = W2 + k * 32 + jb2;
        #pragma unroll
        for (int j = 0; j < 8; ++j) a2[j] = fmaf(hk[k], wr[j], a2[j]);
    }
    #pragma unroll
    for (int j = 0; j < 8; ++j) a2[j] = a2[j] > 0.f ? a2[j] : 0.01f * a2[j];
    #pragma unroll
    for (int j = 0; j < 8; ++j) xt[(64 + jb2 + j) * XT + lane] = a2[j];  // h2t rows 64..95
    __syncthreads();

    // L3 + L4: one thread per node (wave 0)
    if (tid < NPB) {
        float h2k[32];
        #pragma unroll
        for (int k = 0; k < 32; ++k) h2k[k] = xt[(64 + k) * XT + tid];
        float a3[21];
        #pragma unroll
        for (int j = 0; j < 21; ++j) a3[j] = b3[j];
        #pragma unroll
        for (int k = 0; k < 32; ++k) {
            const float* wr = W3 + k * 21;
            #pragma unroll
            for (int j = 0; j < 21; ++j) a3[j] = fmaf(h2k[k], wr[j], a3[j]);
        }
        float s = 0.f;
        #pragma unroll
        for (int k = 0; k < 21; ++k) {
            float v = a3[k] > 0.f ? a3[k] : 0.01f * a3[k];
            s = fmaf(v, W4[k], s);
        }
        int n = nb + tid;
        if (n < NN) out[n] = 1.f / (1.f + expf(-s));
    }
}

extern "C" void kernel_launch(void* const* d_in, const int* in_sizes, int n_in,
                              void* d_out, int out_size, void* d_ws, size_t ws_size,
                              hipStream_t stream) {
    const float* feat = (const float*)d_in[0];
    const int*   index = (const int*)d_in[1];
    const int*   erow = (const int*)d_in[2];
    const int*   ecol = (const int*)d_in[3];
    const float* evalp = (const float*)d_in[4];
    const float* W1 = (const float*)d_in[5];
    const float* b1 = (const float*)d_in[6];
    const float* W2 = (const float*)d_in[7];
    const float* b2 = (const float*)d_in[8];
    const float* W3 = (const float*)d_in[9];
    const float* b3 = (const float*)d_in[10];
    const float* W4 = (const float*)d_in[11];
    float* out = (float*)d_out;

    char* ws = (char*)d_ws;
    size_t off = 0;
    auto alloc = [&](size_t bytes) -> void* {
        void* p = ws + off;
        off += (bytes + 255) & ~(size_t)255;
        return p;
    };
    float* deg     = (float*)alloc((size_t)MM * 4);   // deg+cnt adjacent: one memset
    int*   cnt     = (int*)  alloc((size_t)MM * 4);
    float* dis     = (float*)alloc((size_t)MM * 4);
    int*   rowptr  = (int*)  alloc((size_t)(MM + 1) * 4);
    int*   partial = (int*)  alloc((size_t)MM * 4);
    int*   bsum    = (int*)  alloc((size_t)NB * 4);
    int*   boff    = (int*)  alloc((size_t)NB * 4);
    int*   slot    = (int*)  alloc((size_t)EE * 4);
    int*   col_s   = (int*)  alloc((size_t)EE * 4);
    int*   colf_s  = (int*)  alloc((size_t)EE * 4);
    float* val_s   = (float*)alloc((size_t)EE * 4);
    int*   invidx  = (int*)  alloc((size_t)NN * 4);
    float* Xa      = (float*)alloc((size_t)MM * DD * 4);
    float* Xb      = (float*)alloc((size_t)MM * DD * 4);

    // deg and cnt are adjacent (each 200000 B rounded to 200192): single memset
    hipMemsetAsync(deg, 0, (size_t)((200000 + 255) & ~255) + (size_t)MM * 4, stream);

    deg_count_kernel<<<(EE + 255) / 256, 256, 0, stream>>>(erow, evalp, deg, cnt, slot, invidx);
    fused_setup_kernel<<<NB, 256, 0, stream>>>(deg, dis, index, invidx, cnt, partial, bsum);
    scanB_kernel<<<1, 64, 0, stream>>>(bsum, boff);
    scanC_kernel<<<(MM + 255) / 256, 256, 0, stream>>>(partial, cnt, boff, rowptr);
    scatter_kernel<<<(EE + 255) / 256, 256, 0, stream>>>(erow, ecol, evalp, dis, index,
                                                         rowptr, slot, col_s, colf_s, val_s);

    spmm_kernel<<<(MM + 15) / 16, 256, 0, stream>>>(rowptr, colf_s, val_s, feat, Xa);
    spmm_kernel<<<(MM + 15) / 16, 256, 0, stream>>>(rowptr, col_s, val_s, Xa, Xb);
    spmm_kernel<<<(MM + 15) / 16, 256, 0, stream>>>(rowptr, col_s, val_s, Xb, Xa);

    mlp_kernel<<<(NN + NPB - 1) / NPB, 256, 0, stream>>>(feat, Xa, invidx,
                                                         W1, b1, W2, b2, W3, b3, W4, out);
}

// Round 6
// 348.241 us; speedup vs baseline: 1.4730x; 1.1348x over previous
//
#include <hip/hip_runtime.h>
#include <math.h>

#define NN 100000
#define MM 50000
#define EE 600000
#define DD 128
#define NB 196  // ceil(MM/256)

// ---- bf16 helpers (OCP bf16 = upper 16 bits of f32; RNE rounding) ----
__device__ __forceinline__ float bl(unsigned u) { return __uint_as_float(u << 16); }
__device__ __forceinline__ float bh(unsigned u) { return __uint_as_float(u & 0xFFFF0000u); }
__device__ __forceinline__ unsigned rne(float f) {
    unsigned u = __float_as_uint(f);
    return (u + 0x7FFFu + ((u >> 16) & 1u)) >> 16;
}
__device__ __forceinline__ unsigned pk2(float a, float b) { return rne(a) | (rne(b) << 16); }

// a[0..7] += v * bf16x8(u)
__device__ __forceinline__ void fmab8(float v, uint4 u, float* a) {
    a[0] = fmaf(v, bl(u.x), a[0]); a[1] = fmaf(v, bh(u.x), a[1]);
    a[2] = fmaf(v, bl(u.y), a[2]); a[3] = fmaf(v, bh(u.y), a[3]);
    a[4] = fmaf(v, bl(u.z), a[4]); a[5] = fmaf(v, bh(u.z), a[5]);
    a[6] = fmaf(v, bl(u.w), a[6]); a[7] = fmaf(v, bh(u.w), a[7]);
}

__device__ __forceinline__ void fma21(float h, const float* wrow, float* a) {
    float4 q0 = ((const float4*)wrow)[0];
    float4 q1 = ((const float4*)wrow)[1];
    float4 q2 = ((const float4*)wrow)[2];
    float4 q3 = ((const float4*)wrow)[3];
    float4 q4 = ((const float4*)wrow)[4];
    float4 q5 = ((const float4*)wrow)[5];
    a[0]  = fmaf(h, q0.x, a[0]);  a[1]  = fmaf(h, q0.y, a[1]);
    a[2]  = fmaf(h, q0.z, a[2]);  a[3]  = fmaf(h, q0.w, a[3]);
    a[4]  = fmaf(h, q1.x, a[4]);  a[5]  = fmaf(h, q1.y, a[5]);
    a[6]  = fmaf(h, q1.z, a[6]);  a[7]  = fmaf(h, q1.w, a[7]);
    a[8]  = fmaf(h, q2.x, a[8]);  a[9]  = fmaf(h, q2.y, a[9]);
    a[10] = fmaf(h, q2.z, a[10]); a[11] = fmaf(h, q2.w, a[11]);
    a[12] = fmaf(h, q3.x, a[12]); a[13] = fmaf(h, q3.y, a[13]);
    a[14] = fmaf(h, q3.z, a[14]); a[15] = fmaf(h, q3.w, a[15]);
    a[16] = fmaf(h, q4.x, a[16]); a[17] = fmaf(h, q4.y, a[17]);
    a[18] = fmaf(h, q4.z, a[18]); a[19] = fmaf(h, q4.w, a[19]);
    a[20] = fmaf(h, q5.x, a[20]);
}

// --- degree (weighted) + per-row edge counts + slot assignment + invidx init ---
__global__ void deg_count_kernel(const int* __restrict__ row, const float* __restrict__ val,
                                 float* __restrict__ deg, int* __restrict__ cnt,
                                 int* __restrict__ slot, int* __restrict__ invidx) {
    int e = blockIdx.x * 256 + threadIdx.x;
    if (e < NN) invidx[e] = -1;
    if (e < EE) {
        int r = row[e];
        atomicAdd(&deg[r], val[e]);
        slot[e] = atomicAdd(&cnt[r], 1);
    }
}

// --- fused: dis = rsqrt(deg+eps); invidx[index[i]] = i; scanA over cnt ---
__global__ void fused_setup_kernel(const float* __restrict__ deg, float* __restrict__ dis,
                                   const int* __restrict__ index, int* __restrict__ invidx,
                                   const int* __restrict__ cnt, int* __restrict__ partial,
                                   int* __restrict__ bsum) {
    __shared__ int ws[4];
    int tid = threadIdx.x, lane = tid & 63, w = tid >> 6;
    int i = blockIdx.x * 256 + tid;
    if (i < MM) {
        dis[i] = rsqrtf(deg[i] + 1e-8f);
        invidx[index[i]] = i;
    }
    int v = (i < MM) ? cnt[i] : 0;
    int x = v;
    #pragma unroll
    for (int off = 1; off < 64; off <<= 1) {
        int t = __shfl_up(x, off, 64);
        if (lane >= off) x += t;
    }
    if (lane == 63) ws[w] = x;
    __syncthreads();
    int add = 0;
    for (int q = 0; q < w; ++q) add += ws[q];
    x += add;
    if (i < MM) partial[i] = x;
    if (tid == 255) bsum[blockIdx.x] = x;
}

__global__ void scanB_kernel(const int* __restrict__ bsum, int* __restrict__ boff) {
    int lane = threadIdx.x;  // 64 threads
    int carry = 0;
    for (int base = 0; base < NB; base += 64) {
        int v = (base + lane < NB) ? bsum[base + lane] : 0;
        int x = v;
        #pragma unroll
        for (int off = 1; off < 64; off <<= 1) {
            int t = __shfl_up(x, off, 64);
            if (lane >= off) x += t;
        }
        if (base + lane < NB) boff[base + lane] = carry + x - v;
        carry += __shfl(x, 63);
    }
}

__global__ void scanC_kernel(const int* __restrict__ partial, const int* __restrict__ cnt,
                             const int* __restrict__ boff, int* __restrict__ rowptr) {
    int i = blockIdx.x * 256 + threadIdx.x;
    if (i < MM) rowptr[i] = partial[i] - cnt[i] + boff[i >> 8];
    if (i == 0) rowptr[MM] = EE;
}

// --- bucket edges by row (atomic-free: pos = rowptr[r] + slot[e]) ---
__global__ void scatter_kernel(const int* __restrict__ row, const int* __restrict__ col,
                               const float* __restrict__ val, const float* __restrict__ dis,
                               const int* __restrict__ rowptr, const int* __restrict__ slot,
                               int* __restrict__ col_s, float* __restrict__ val_s) {
    int e = blockIdx.x * 256 + threadIdx.x;
    if (e < EE) {
        int r = row[e], c = col[e];
        int pos = rowptr[r] + slot[e];
        col_s[pos] = c;
        val_s[pos] = val[e] * dis[r] * dis[c];
    }
}

// --- X0b = bf16(features[index]) packed pairs: [MM][64] uints ---
__global__ void cvt_kernel(const float* __restrict__ feat, const int* __restrict__ index,
                           unsigned* __restrict__ X0b) {
    int i = blockIdx.x * 256 + threadIdx.x;
    if (i < MM * 64) {
        int node = i >> 6, k2 = i & 63;
        int idx = index[node];
        float2 f = ((const float2*)feat)[(size_t)idx * 64 + k2];
        X0b[i] = pk2(f.x, f.y);
    }
}

// --- SpMM on bf16 tables: 16-lane group per row, 4 groups/wave; 1 uint4 gather/edge ---
__global__ __launch_bounds__(256) void spmm_kernel(
    const int* __restrict__ rowptr, const int* __restrict__ cols,
    const float* __restrict__ vals, const unsigned short* __restrict__ X,
    unsigned short* __restrict__ Y) {
    int lane = threadIdx.x & 63;
    int wid = threadIdx.x >> 6;
    int g = lane >> 4, sub = lane & 15;
    int r = blockIdx.x * 16 + wid * 4 + g;
    bool valid = (r < MM);
    int rc = valid ? r : (MM - 1);
    int s = rowptr[rc], e = rowptr[rc + 1];
    const uint4* __restrict__ X4 = (const uint4*)X;
    float a[8] = {0.f, 0.f, 0.f, 0.f, 0.f, 0.f, 0.f, 0.f};
    for (int base = s; base < e; base += 16) {
        int cnt = min(16, e - base);
        int c = 0; float v = 0.f;
        if (sub < cnt) { c = cols[base + sub]; v = vals[base + sub]; }
        int j = 0;
        for (; j + 4 <= cnt; j += 4) {
            int c0 = __shfl(c, g * 16 + j);     float v0 = __shfl(v, g * 16 + j);
            int c1 = __shfl(c, g * 16 + j + 1); float v1 = __shfl(v, g * 16 + j + 1);
            int c2 = __shfl(c, g * 16 + j + 2); float v2 = __shfl(v, g * 16 + j + 2);
            int c3 = __shfl(c, g * 16 + j + 3); float v3 = __shfl(v, g * 16 + j + 3);
            uint4 u0 = X4[(size_t)c0 * 16 + sub];
            uint4 u1 = X4[(size_t)c1 * 16 + sub];
            uint4 u2 = X4[(size_t)c2 * 16 + sub];
            uint4 u3 = X4[(size_t)c3 * 16 + sub];
            fmab8(v0, u0, a);
            fmab8(v1, u1, a);
            fmab8(v2, u2, a);
            fmab8(v3, u3, a);
        }
        for (; j < cnt; ++j) {
            int cc = __shfl(c, g * 16 + j); float vv = __shfl(v, g * 16 + j);
            uint4 u0 = X4[(size_t)cc * 16 + sub];
            fmab8(vv, u0, a);
        }
    }
    if (valid) {
        uint4 o;
        o.x = pk2(a[0], a[1]); o.y = pk2(a[2], a[3]);
        o.z = pk2(a[4], a[5]); o.w = pk2(a[6], a[7]);
        ((uint4*)Y)[(size_t)r * 16 + sub] = o;
    }
}

// --- MLP head: bf16 weights + x in LDS, wave-uniform broadcast reads, no SMEM in loop ---
#define NPB 64
#define XTS 65   // uint stride: bank-rotating, conflict-free for all access patterns here

__global__ __launch_bounds__(256, 4) void mlp_kernel(
    const float* __restrict__ feat, const unsigned short* __restrict__ X3,
    const int* __restrict__ invidx,
    const float* __restrict__ W1, const float* __restrict__ b1,
    const float* __restrict__ W2, const float* __restrict__ b2,
    const float* __restrict__ W3, const float* __restrict__ b3,
    const float* __restrict__ W4, float* __restrict__ out) {
    __shared__ unsigned xtp[64 * XTS];   // 16640 B: x pairs [k2][node]; rows 0..31 reused for h1, 32..47 for h2
    __shared__ unsigned W1Ls[4096];      // 16 KB: bf16 pairs [k][j2]
    __shared__ unsigned W2Ls[1024];      // 4 KB
    __shared__ float    W3Ls[768];       // 3 KB: f32 [k][24] (21 used, padded)
    __shared__ float    b1s[64], b2s[32], b3s[24], W4s[24];
    int tid = threadIdx.x;
    int nb = blockIdx.x * NPB;

    for (int u = tid; u < 4096; u += 256) {
        int k = u >> 5, j2 = u & 31;
        float2 wf = ((const float2*)W1)[(k << 5) + j2];
        W1Ls[u] = pk2(wf.x, wf.y);
    }
    for (int u = tid; u < 1024; u += 256) {
        int k = u >> 4, j2 = u & 15;
        float2 wf = ((const float2*)W2)[(k << 4) + j2];
        W2Ls[u] = pk2(wf.x, wf.y);
    }
    for (int u = tid; u < 768; u += 256) {
        int k = u / 24, j = u - k * 24;
        W3Ls[u] = (j < 21) ? W3[k * 21 + j] : 0.f;
    }
    if (tid < 64) b1s[tid] = b1[tid];
    if (tid < 32) b2s[tid] = b2[tid];
    if (tid < 24) { b3s[tid] = (tid < 21) ? b3[tid] : 0.f; W4s[tid] = (tid < 21) ? W4[tid] : 0.f; }

    // stage x (bf16 pairs, transposed [k2][node]); node is wave-uniform per iteration
    #pragma unroll 4
    for (int it = 0; it < 16; ++it) {
        int i = it * 256 + tid;
        int node = i >> 6, k2 = i & 63;
        int n = nb + node;
        unsigned p = 0;
        if (n < NN) {
            int q = invidx[n];
            if (q >= 0) p = ((const unsigned*)X3)[(size_t)q * 64 + k2];
            else { float2 f = ((const float2*)feat)[(size_t)n * 64 + k2]; p = pk2(f.x, f.y); }
        }
        xtp[k2 * XTS + node] = p;
    }
    __syncthreads();

    int lane = tid & 63, w = tid >> 6;
    int jb = __builtin_amdgcn_readfirstlane(w * 16);   // wave-uniform j-chunk

    // L1: h1[jb..jb+16) for node=lane
    float acc[16];
    #pragma unroll
    for (int j = 0; j < 16; ++j) acc[j] = b1s[jb + j];
    #pragma unroll 4
    for (int k2 = 0; k2 < 64; ++k2) {
        unsigned xu = xtp[k2 * XTS + lane];
        float xl = bl(xu), xh = bh(xu);
        const uint4* w0p = (const uint4*)&W1Ls[(k2 * 2) * 32 + (jb >> 1)];
        uint4 r0 = w0p[0], r1 = w0p[1];
        const uint4* w1p = (const uint4*)&W1Ls[(k2 * 2 + 1) * 32 + (jb >> 1)];
        uint4 r2 = w1p[0], r3 = w1p[1];
        fmab8(xl, r0, acc);     fmab8(xl, r1, acc + 8);
        fmab8(xh, r2, acc);     fmab8(xh, r3, acc + 8);
    }
    #pragma unroll
    for (int j = 0; j < 16; ++j) acc[j] = acc[j] > 0.f ? acc[j] : 0.01f * acc[j];
    __syncthreads();   // all waves done reading x
    #pragma unroll
    for (int t = 0; t < 8; ++t) xtp[((jb >> 1) + t) * XTS + lane] = pk2(acc[2 * t], acc[2 * t + 1]);
    __syncthreads();

    // L2: h2[jb2..jb2+8)
    int jb2 = __builtin_amdgcn_readfirstlane(w * 8);
    float a2[8];
    #pragma unroll
    for (int j = 0; j < 8; ++j) a2[j] = b2s[jb2 + j];
    #pragma unroll 4
    for (int k2 = 0; k2 < 32; ++k2) {
        unsigned hu = xtp[k2 * XTS + lane];
        float hl = bl(hu), hh = bh(hu);
        uint4 r0 = *(const uint4*)&W2Ls[(k2 * 2) * 16 + (jb2 >> 1)];
        uint4 r1 = *(const uint4*)&W2Ls[(k2 * 2 + 1) * 16 + (jb2 >> 1)];
        fmab8(hl, r0, a2);
        fmab8(hh, r1, a2);
    }
    #pragma unroll
    for (int j = 0; j < 8; ++j) a2[j] = a2[j] > 0.f ? a2[j] : 0.01f * a2[j];
    #pragma unroll
    for (int t = 0; t < 4; ++t) xtp[(32 + (jb2 >> 1) + t) * XTS + lane] = pk2(a2[2 * t], a2[2 * t + 1]);
    __syncthreads();

    // L3 + L4: each wave handles its 16 nodes (lanes 16..63 redundantly compute, don't store)
    int node = (w << 4) + (lane & 15);
    float a3[21];
    #pragma unroll
    for (int j = 0; j < 21; ++j) a3[j] = b3s[j];
    #pragma unroll 4
    for (int k2 = 0; k2 < 16; ++k2) {
        unsigned hu = xtp[(32 + k2) * XTS + node];
        float h0 = bl(hu), h1v = bh(hu);
        fma21(h0, &W3Ls[(k2 * 2) * 24], a3);
        fma21(h1v, &W3Ls[(k2 * 2 + 1) * 24], a3);
    }
    float s = 0.f;
    #pragma unroll
    for (int j = 0; j < 21; ++j) {
        float vj = a3[j] > 0.f ? a3[j] : 0.01f * a3[j];
        s = fmaf(vj, W4s[j], s);
    }
    if ((lane >> 4) == 0) {
        int n = nb + node;
        if (n < NN) out[n] = 1.f / (1.f + expf(-s));
    }
}

extern "C" void kernel_launch(void* const* d_in, const int* in_sizes, int n_in,
                              void* d_out, int out_size, void* d_ws, size_t ws_size,
                              hipStream_t stream) {
    const float* feat = (const float*)d_in[0];
    const int*   index = (const int*)d_in[1];
    const int*   erow = (const int*)d_in[2];
    const int*   ecol = (const int*)d_in[3];
    const float* evalp = (const float*)d_in[4];
    const float* W1 = (const float*)d_in[5];
    const float* b1 = (const float*)d_in[6];
    const float* W2 = (const float*)d_in[7];
    const float* b2 = (const float*)d_in[8];
    const float* W3 = (const float*)d_in[9];
    const float* b3 = (const float*)d_in[10];
    const float* W4 = (const float*)d_in[11];
    float* out = (float*)d_out;

    char* ws = (char*)d_ws;
    size_t off = 0;
    auto alloc = [&](size_t bytes) -> void* {
        void* p = ws + off;
        off += (bytes + 255) & ~(size_t)255;
        return p;
    };
    float* deg     = (float*)alloc((size_t)MM * 4);   // deg+cnt adjacent: one memset
    int*   cnt     = (int*)  alloc((size_t)MM * 4);
    float* dis     = (float*)alloc((size_t)MM * 4);
    int*   rowptr  = (int*)  alloc((size_t)(MM + 1) * 4);
    int*   partial = (int*)  alloc((size_t)MM * 4);
    int*   bsum    = (int*)  alloc((size_t)NB * 4);
    int*   boff    = (int*)  alloc((size_t)NB * 4);
    int*   slot    = (int*)  alloc((size_t)EE * 4);
    int*   col_s   = (int*)  alloc((size_t)EE * 4);
    float* val_s   = (float*)alloc((size_t)EE * 4);
    int*   invidx  = (int*)  alloc((size_t)NN * 4);
    unsigned*       X0b = (unsigned*)      alloc((size_t)MM * DD * 2);
    unsigned short* Xa  = (unsigned short*)alloc((size_t)MM * DD * 2);
    unsigned short* Xb  = (unsigned short*)alloc((size_t)MM * DD * 2);

    // deg and cnt are adjacent: single memset covers both
    hipMemsetAsync(deg, 0, (size_t)((MM * 4 + 255) & ~255) + (size_t)MM * 4, stream);

    deg_count_kernel<<<(EE + 255) / 256, 256, 0, stream>>>(erow, evalp, deg, cnt, slot, invidx);
    fused_setup_kernel<<<NB, 256, 0, stream>>>(deg, dis, index, invidx, cnt, partial, bsum);
    scanB_kernel<<<1, 64, 0, stream>>>(bsum, boff);
    scanC_kernel<<<(MM + 255) / 256, 256, 0, stream>>>(partial, cnt, boff, rowptr);
    scatter_kernel<<<(EE + 255) / 256, 256, 0, stream>>>(erow, ecol, evalp, dis,
                                                         rowptr, slot, col_s, val_s);
    cvt_kernel<<<(MM * 64 + 255) / 256, 256, 0, stream>>>(feat, index, X0b);

    spmm_kernel<<<(MM + 15) / 16, 256, 0, stream>>>(rowptr, col_s, val_s,
                                                    (const unsigned short*)X0b, Xa);
    spmm_kernel<<<(MM + 15) / 16, 256, 0, stream>>>(rowptr, col_s, val_s, Xa, Xb);
    spmm_kernel<<<(MM + 15) / 16, 256, 0, stream>>>(rowptr, col_s, val_s, Xb, Xa);

    mlp_kernel<<<(NN + NPB - 1) / NPB, 256, 0, stream>>>(feat, Xa, invidx,
                                                         W1, b1, W2, b2, W3, b3, W4, out);
}

// Round 7
// 307.102 us; speedup vs baseline: 1.6704x; 1.1340x over previous
//
#include <hip/hip_runtime.h>
#include <math.h>

#define NN 100000
#define MM 50000
#define EE 600000
#define DD 128
#define NB 196  // ceil(MM/256)

typedef short bf16x8 __attribute__((ext_vector_type(8)));
typedef float f32x4 __attribute__((ext_vector_type(4)));

// ---- bf16 helpers (upper 16 bits of f32; RNE rounding) ----
__device__ __forceinline__ float bl(unsigned u) { return __uint_as_float(u << 16); }
__device__ __forceinline__ float bh(unsigned u) { return __uint_as_float(u & 0xFFFF0000u); }
__device__ __forceinline__ unsigned rne(float f) {
    unsigned u = __float_as_uint(f);
    return (u + 0x7FFFu + ((u >> 16) & 1u)) >> 16;
}
__device__ __forceinline__ unsigned pk2(float a, float b) { return rne(a) | (rne(b) << 16); }

// a[0..7] += v * bf16x8(u)   (spmm inner op)
__device__ __forceinline__ void fmab8(float v, uint4 u, float* a) {
    a[0] = fmaf(v, bl(u.x), a[0]); a[1] = fmaf(v, bh(u.x), a[1]);
    a[2] = fmaf(v, bl(u.y), a[2]); a[3] = fmaf(v, bh(u.y), a[3]);
    a[4] = fmaf(v, bl(u.z), a[4]); a[5] = fmaf(v, bh(u.z), a[5]);
    a[6] = fmaf(v, bl(u.w), a[6]); a[7] = fmaf(v, bh(u.w), a[7]);
}

__device__ __forceinline__ void fma21(float h, const float* wrow, float* a) {
    #pragma unroll
    for (int j = 0; j < 21; ++j) a[j] = fmaf(h, wrow[j], a[j]);
}

// --- degree (weighted) + per-row edge counts + slot assignment + invidx init ---
__global__ void deg_count_kernel(const int* __restrict__ row, const float* __restrict__ val,
                                 float* __restrict__ deg, int* __restrict__ cnt,
                                 int* __restrict__ slot, int* __restrict__ invidx) {
    int e = blockIdx.x * 256 + threadIdx.x;
    if (e < NN) invidx[e] = -1;
    if (e < EE) {
        int r = row[e];
        atomicAdd(&deg[r], val[e]);
        slot[e] = atomicAdd(&cnt[r], 1);
    }
}

// --- fused: dis = rsqrt(deg+eps); invidx[index[i]] = i; scanA over cnt ---
__global__ void fused_setup_kernel(const float* __restrict__ deg, float* __restrict__ dis,
                                   const int* __restrict__ index, int* __restrict__ invidx,
                                   const int* __restrict__ cnt, int* __restrict__ partial,
                                   int* __restrict__ bsum) {
    __shared__ int ws[4];
    int tid = threadIdx.x, lane = tid & 63, w = tid >> 6;
    int i = blockIdx.x * 256 + tid;
    if (i < MM) {
        dis[i] = rsqrtf(deg[i] + 1e-8f);
        invidx[index[i]] = i;
    }
    int v = (i < MM) ? cnt[i] : 0;
    int x = v;
    #pragma unroll
    for (int off = 1; off < 64; off <<= 1) {
        int t = __shfl_up(x, off, 64);
        if (lane >= off) x += t;
    }
    if (lane == 63) ws[w] = x;
    __syncthreads();
    int add = 0;
    for (int q = 0; q < w; ++q) add += ws[q];
    x += add;
    if (i < MM) partial[i] = x;
    if (tid == 255) bsum[blockIdx.x] = x;
}

__global__ void scanB_kernel(const int* __restrict__ bsum, int* __restrict__ boff) {
    int lane = threadIdx.x;  // 64 threads
    int carry = 0;
    for (int base = 0; base < NB; base += 64) {
        int v = (base + lane < NB) ? bsum[base + lane] : 0;
        int x = v;
        #pragma unroll
        for (int off = 1; off < 64; off <<= 1) {
            int t = __shfl_up(x, off, 64);
            if (lane >= off) x += t;
        }
        if (base + lane < NB) boff[base + lane] = carry + x - v;
        carry += __shfl(x, 63);
    }
}

__global__ void scanC_kernel(const int* __restrict__ partial, const int* __restrict__ cnt,
                             const int* __restrict__ boff, int* __restrict__ rowptr) {
    int i = blockIdx.x * 256 + threadIdx.x;
    if (i < MM) rowptr[i] = partial[i] - cnt[i] + boff[i >> 8];
    if (i == 0) rowptr[MM] = EE;
}

// --- bucket edges by row (atomic-free: pos = rowptr[r] + slot[e]) ---
__global__ void scatter_kernel(const int* __restrict__ row, const int* __restrict__ col,
                               const float* __restrict__ val, const float* __restrict__ dis,
                               const int* __restrict__ rowptr, const int* __restrict__ slot,
                               int* __restrict__ col_s, float* __restrict__ val_s) {
    int e = blockIdx.x * 256 + threadIdx.x;
    if (e < EE) {
        int r = row[e], c = col[e];
        int pos = rowptr[r] + slot[e];
        col_s[pos] = c;
        val_s[pos] = val[e] * dis[r] * dis[c];
    }
}

// --- X0b = bf16(features[index]) packed pairs: [MM][64] uints ---
__global__ void cvt_kernel(const float* __restrict__ feat, const int* __restrict__ index,
                           unsigned* __restrict__ X0b) {
    int i = blockIdx.x * 256 + threadIdx.x;
    if (i < MM * 64) {
        int node = i >> 6, k2 = i & 63;
        int idx = index[node];
        float2 f = ((const float2*)feat)[(size_t)idx * 64 + k2];
        X0b[i] = pk2(f.x, f.y);
    }
}

// --- SpMM on bf16 tables: 16-lane group per row, 4 groups/wave; 1 uint4 gather/edge ---
__global__ __launch_bounds__(256) void spmm_kernel(
    const int* __restrict__ rowptr, const int* __restrict__ cols,
    const float* __restrict__ vals, const unsigned short* __restrict__ X,
    unsigned short* __restrict__ Y) {
    int lane = threadIdx.x & 63;
    int wid = threadIdx.x >> 6;
    int g = lane >> 4, sub = lane & 15;
    int r = blockIdx.x * 16 + wid * 4 + g;
    bool valid = (r < MM);
    int rc = valid ? r : (MM - 1);
    int s = rowptr[rc], e = rowptr[rc + 1];
    const uint4* __restrict__ X4 = (const uint4*)X;
    float a[8] = {0.f, 0.f, 0.f, 0.f, 0.f, 0.f, 0.f, 0.f};
    for (int base = s; base < e; base += 16) {
        int cnt = min(16, e - base);
        int c = 0; float v = 0.f;
        if (sub < cnt) { c = cols[base + sub]; v = vals[base + sub]; }
        int j = 0;
        for (; j + 4 <= cnt; j += 4) {
            int c0 = __shfl(c, g * 16 + j);     float v0 = __shfl(v, g * 16 + j);
            int c1 = __shfl(c, g * 16 + j + 1); float v1 = __shfl(v, g * 16 + j + 1);
            int c2 = __shfl(c, g * 16 + j + 2); float v2 = __shfl(v, g * 16 + j + 2);
            int c3 = __shfl(c, g * 16 + j + 3); float v3 = __shfl(v, g * 16 + j + 3);
            uint4 u0 = X4[(size_t)c0 * 16 + sub];
            uint4 u1 = X4[(size_t)c1 * 16 + sub];
            uint4 u2 = X4[(size_t)c2 * 16 + sub];
            uint4 u3 = X4[(size_t)c3 * 16 + sub];
            fmab8(v0, u0, a);
            fmab8(v1, u1, a);
            fmab8(v2, u2, a);
            fmab8(v3, u3, a);
        }
        for (; j < cnt; ++j) {
            int cc = __shfl(c, g * 16 + j); float vv = __shfl(v, g * 16 + j);
            uint4 u0 = X4[(size_t)cc * 16 + sub];
            fmab8(vv, u0, a);
        }
    }
    if (valid) {
        uint4 o;
        o.x = pk2(a[0], a[1]); o.y = pk2(a[2], a[3]);
        o.z = pk2(a[4], a[5]); o.w = pk2(a[6], a[7]);
        ((uint4*)Y)[(size_t)r * 16 + sub] = o;
    }
}

// --- MFMA MLP head: 64 nodes/block, 4 waves, each wave = 16 nodes.
//     L1: [16x64] = 4 j-tiles x 4 k-chunks of mfma_f32_16x16x32_bf16
//     L2: [16x32] = 2 j-tiles x 2 k-chunks
//     L3+L4 scalar tail (s_load weights).
//     LDS rows padded to 272B/144B: b128 frag reads land 2 lanes/bank (free). ---
#define NPB 64
#define XSW 136   // x row stride in shorts (272B)
#define H1W 72    // h1/W2t row stride in shorts (144B)

__global__ __launch_bounds__(256) void mlp_kernel(
    const float* __restrict__ feat, const unsigned short* __restrict__ X3,
    const int* __restrict__ invidx,
    const float* __restrict__ W1, const float* __restrict__ b1,
    const float* __restrict__ W2, const float* __restrict__ b2,
    const float* __restrict__ W3, const float* __restrict__ b3,
    const float* __restrict__ W4, float* __restrict__ out) {
    __shared__ char smem[17408 + 17408 + 4608];   // 39424 B -> 4 blocks/CU
    short* xs  = (short*)smem;                    // [64][136] bf16 x rows
    short* h1s = (short*)smem;                    // overlay after L1: [64][72]
    short* w1t = (short*)(smem + 17408);          // [64 j][136] bf16 W1^T
    float* h2f = (float*)(smem + 17408);          // overlay after L2: [64][36] f32
    short* w2t = (short*)(smem + 17408 + 17408);  // [32 j][72] bf16 W2^T

    int tid = threadIdx.x;
    int nb = blockIdx.x * NPB;

    // stage x: 64 rows of 64 uints (bf16 pairs); one wave per row-iteration
    #pragma unroll 4
    for (int it = 0; it < 16; ++it) {
        int i = it * 256 + tid;
        int node = i >> 6, u = i & 63;
        int n = nb + node;
        unsigned p = 0;
        if (n < NN) {
            int q = invidx[n];
            if (q >= 0) p = ((const unsigned*)X3)[(size_t)q * 64 + u];
            else { float2 f = ((const float2*)feat)[(size_t)n * 64 + u]; p = pk2(f.x, f.y); }
        }
        ((unsigned*)xs)[0]; // no-op
        *((unsigned*)(xs + node * XSW) + u) = p;
    }
    // stage W1^T as bf16 pairs: thread u -> j=u&63, kpair=u>>6
    #pragma unroll 4
    for (int it = 0; it < 16; ++it) {
        int u = it * 256 + tid;
        int j = u & 63, kp = u >> 6;
        float w0 = W1[(2 * kp) * 64 + j], w1 = W1[(2 * kp + 1) * 64 + j];
        *((unsigned*)(w1t + j * XSW) + kp) = pk2(w0, w1);
    }
    // stage W2^T: thread u -> j=u&31, kpair=u>>5 (1024 elems)
    #pragma unroll
    for (int it = 0; it < 4; ++it) {
        int u = it * 256 + tid;
        int j = u & 31, kp = u >> 5;
        float w0 = W2[(2 * kp) * 32 + j], w1 = W2[(2 * kp + 1) * 32 + j];
        *((unsigned*)(w2t + j * H1W) + kp) = pk2(w0, w1);
    }
    __syncthreads();

    int lane = tid & 63, w = tid >> 6;
    int p = lane & 15, q = lane >> 4;

    // ---- L1: nodes w*16..w*16+15, all 64 outputs ----
    bf16x8 af[4];
    #pragma unroll
    for (int kc = 0; kc < 4; ++kc)
        af[kc] = *(const bf16x8*)(xs + (w * 16 + p) * XSW + kc * 32 + q * 8);

    f32x4 acc[4];
    #pragma unroll
    for (int jt = 0; jt < 4; ++jt) {
        float bv = b1[jt * 16 + p];
        acc[jt][0] = bv; acc[jt][1] = bv; acc[jt][2] = bv; acc[jt][3] = bv;
    }
    #pragma unroll
    for (int jt = 0; jt < 4; ++jt) {
        #pragma unroll
        for (int kc = 0; kc < 4; ++kc) {
            bf16x8 bf = *(const bf16x8*)(w1t + (jt * 16 + p) * XSW + kc * 32 + q * 8);
            acc[jt] = __builtin_amdgcn_mfma_f32_16x16x32_bf16(af[kc], bf, acc[jt], 0, 0, 0);
        }
    }
    __syncthreads();   // xs dead; safe to overlay h1
    #pragma unroll
    for (int jt = 0; jt < 4; ++jt) {
        #pragma unroll
        for (int r = 0; r < 4; ++r) {
            float v = acc[jt][r];
            v = v > 0.f ? v : 0.01f * v;
            h1s[(w * 16 + q * 4 + r) * H1W + jt * 16 + p] = (short)rne(v);
        }
    }
    __syncthreads();

    // ---- L2: nodes w*16..+15, 32 outputs ----
    bf16x8 a2f[2];
    #pragma unroll
    for (int kc = 0; kc < 2; ++kc)
        a2f[kc] = *(const bf16x8*)(h1s + (w * 16 + p) * H1W + kc * 32 + q * 8);
    f32x4 acc2[2];
    #pragma unroll
    for (int jt = 0; jt < 2; ++jt) {
        float bv = b2[jt * 16 + p];
        acc2[jt][0] = bv; acc2[jt][1] = bv; acc2[jt][2] = bv; acc2[jt][3] = bv;
        #pragma unroll
        for (int kc = 0; kc < 2; ++kc) {
            bf16x8 bf = *(const bf16x8*)(w2t + (jt * 16 + p) * H1W + kc * 32 + q * 8);
            acc2[jt] = __builtin_amdgcn_mfma_f32_16x16x32_bf16(a2f[kc], bf, acc2[jt], 0, 0, 0);
        }
    }
    __syncthreads();   // w1t dead; safe to overlay h2f
    #pragma unroll
    for (int jt = 0; jt < 2; ++jt) {
        #pragma unroll
        for (int r = 0; r < 4; ++r) {
            float v = acc2[jt][r];
            v = v > 0.f ? v : 0.01f * v;
            h2f[(w * 16 + q * 4 + r) * 36 + jt * 16 + p] = v;
        }
    }
    __syncthreads();

    // ---- L3+L4 scalar tail: each wave its 16 nodes; q-groups redundant ----
    int node = w * 16 + p;
    float a3[21];
    #pragma unroll
    for (int j = 0; j < 21; ++j) a3[j] = b3[j];
    #pragma unroll 4
    for (int k = 0; k < 32; ++k) {
        float hk = h2f[node * 36 + k];
        fma21(hk, W3 + k * 21, a3);
    }
    float s = 0.f;
    #pragma unroll
    for (int j = 0; j < 21; ++j) {
        float vj = a3[j] > 0.f ? a3[j] : 0.01f * a3[j];
        s = fmaf(vj, W4[j], s);
    }
    if (q == 0) {
        int n = nb + node;
        if (n < NN) out[n] = 1.f / (1.f + expf(-s));
    }
}

extern "C" void kernel_launch(void* const* d_in, const int* in_sizes, int n_in,
                              void* d_out, int out_size, void* d_ws, size_t ws_size,
                              hipStream_t stream) {
    const float* feat = (const float*)d_in[0];
    const int*   index = (const int*)d_in[1];
    const int*   erow = (const int*)d_in[2];
    const int*   ecol = (const int*)d_in[3];
    const float* evalp = (const float*)d_in[4];
    const float* W1 = (const float*)d_in[5];
    const float* b1 = (const float*)d_in[6];
    const float* W2 = (const float*)d_in[7];
    const float* b2 = (const float*)d_in[8];
    const float* W3 = (const float*)d_in[9];
    const float* b3 = (const float*)d_in[10];
    const float* W4 = (const float*)d_in[11];
    float* out = (float*)d_out;

    char* ws = (char*)d_ws;
    size_t off = 0;
    auto alloc = [&](size_t bytes) -> void* {
        void* p = ws + off;
        off += (bytes + 255) & ~(size_t)255;
        return p;
    };
    float* deg     = (float*)alloc((size_t)MM * 4);   // deg+cnt adjacent: one memset
    int*   cnt     = (int*)  alloc((size_t)MM * 4);
    float* dis     = (float*)alloc((size_t)MM * 4);
    int*   rowptr  = (int*)  alloc((size_t)(MM + 1) * 4);
    int*   partial = (int*)  alloc((size_t)MM * 4);
    int*   bsum    = (int*)  alloc((size_t)NB * 4);
    int*   boff    = (int*)  alloc((size_t)NB * 4);
    int*   slot    = (int*)  alloc((size_t)EE * 4);
    int*   col_s   = (int*)  alloc((size_t)EE * 4);
    float* val_s   = (float*)alloc((size_t)EE * 4);
    int*   invidx  = (int*)  alloc((size_t)NN * 4);
    unsigned*       X0b = (unsigned*)      alloc((size_t)MM * DD * 2);
    unsigned short* Xa  = (unsigned short*)alloc((size_t)MM * DD * 2);
    unsigned short* Xb  = (unsigned short*)alloc((size_t)MM * DD * 2);

    // deg and cnt are adjacent: single memset covers both
    hipMemsetAsync(deg, 0, (size_t)((MM * 4 + 255) & ~255) + (size_t)MM * 4, stream);

    deg_count_kernel<<<(EE + 255) / 256, 256, 0, stream>>>(erow, evalp, deg, cnt, slot, invidx);
    fused_setup_kernel<<<NB, 256, 0, stream>>>(deg, dis, index, invidx, cnt, partial, bsum);
    scanB_kernel<<<1, 64, 0, stream>>>(bsum, boff);
    scanC_kernel<<<(MM + 255) / 256, 256, 0, stream>>>(partial, cnt, boff, rowptr);
    scatter_kernel<<<(EE + 255) / 256, 256, 0, stream>>>(erow, ecol, evalp, dis,
                                                         rowptr, slot, col_s, val_s);
    cvt_kernel<<<(MM * 64 + 255) / 256, 256, 0, stream>>>(feat, index, X0b);

    spmm_kernel<<<(MM + 15) / 16, 256, 0, stream>>>(rowptr, col_s, val_s,
                                                    (const unsigned short*)X0b, Xa);
    spmm_kernel<<<(MM + 15) / 16, 256, 0, stream>>>(rowptr, col_s, val_s, Xa, Xb);
    spmm_kernel<<<(MM + 15) / 16, 256, 0, stream>>>(rowptr, col_s, val_s, Xb, Xa);

    mlp_kernel<<<(NN + NPB - 1) / NPB, 256, 0, stream>>>(feat, Xa, invidx,
                                                         W1, b1, W2, b2, W3, b3, W4, out);
}

// Round 8
// 269.235 us; speedup vs baseline: 1.9053x; 1.1406x over previous
//
#include <hip/hip_runtime.h>
#include <math.h>

#define NN 100000
#define MM 50000
#define EE 600000
#define DD 128
#define NB 196  // ceil(MM/256)

typedef short bf16x8 __attribute__((ext_vector_type(8)));
typedef float f32x4 __attribute__((ext_vector_type(4)));

// ---- bf16 helpers (upper 16 bits of f32; RNE rounding) ----
__device__ __forceinline__ float bl(unsigned u) { return __uint_as_float(u << 16); }
__device__ __forceinline__ float bh(unsigned u) { return __uint_as_float(u & 0xFFFF0000u); }
__device__ __forceinline__ unsigned rne(float f) {
    unsigned u = __float_as_uint(f);
    return (u + 0x7FFFu + ((u >> 16) & 1u)) >> 16;
}
__device__ __forceinline__ unsigned pk2(float a, float b) { return rne(a) | (rne(b) << 16); }

// a[0..7] += v * bf16x8(u)   (spmm inner op)
__device__ __forceinline__ void fmab8(float v, uint4 u, float* a) {
    a[0] = fmaf(v, bl(u.x), a[0]); a[1] = fmaf(v, bh(u.x), a[1]);
    a[2] = fmaf(v, bl(u.y), a[2]); a[3] = fmaf(v, bh(u.y), a[3]);
    a[4] = fmaf(v, bl(u.z), a[4]); a[5] = fmaf(v, bh(u.z), a[5]);
    a[6] = fmaf(v, bl(u.w), a[6]); a[7] = fmaf(v, bh(u.w), a[7]);
}

__device__ __forceinline__ void fma21(float h, const float* wrow, float* a) {
    #pragma unroll
    for (int j = 0; j < 21; ++j) a[j] = fmaf(h, wrow[j], a[j]);
}

// --- degree+count via ONE packed 64-bit atomic per edge:
//     bits [44..63] = edge count, bits [0..43] = sum(val * 2^32) fixed-point.
//     (val*2^32 is an exact exponent shift; max row count ~40 -> no overflow) ---
__global__ void deg_count_kernel(const int* __restrict__ row, const float* __restrict__ val,
                                 unsigned long long* __restrict__ dcpack,
                                 int* __restrict__ slot, int* __restrict__ invidx) {
    int e = blockIdx.x * 256 + threadIdx.x;
    if (e < NN) invidx[e] = -1;
    if (e < EE) {
        int r = row[e];
        unsigned long long add = (1ULL << 44) | (unsigned long long)(val[e] * 4294967296.0f);
        unsigned long long old = atomicAdd(&dcpack[r], add);
        slot[e] = (int)(old >> 44);
    }
}

// --- fused: unpack deg/cnt; dis = rsqrt(deg+eps); invidx[index[i]] = i; scanA over cnt ---
__global__ void fused_setup_kernel(const unsigned long long* __restrict__ dcpack,
                                   float* __restrict__ dis,
                                   const int* __restrict__ index, int* __restrict__ invidx,
                                   int* __restrict__ cnt, int* __restrict__ partial,
                                   int* __restrict__ bsum) {
    __shared__ int ws[4];
    int tid = threadIdx.x, lane = tid & 63, w = tid >> 6;
    int i = blockIdx.x * 256 + tid;
    int v = 0;
    if (i < MM) {
        unsigned long long pkv = dcpack[i];
        v = (int)(pkv >> 44);
        float dsum = (float)(pkv & ((1ULL << 44) - 1)) * (1.0f / 4294967296.0f);
        dis[i] = rsqrtf(dsum + 1e-8f);
        invidx[index[i]] = i;
        cnt[i] = v;
    }
    int x = v;
    #pragma unroll
    for (int off = 1; off < 64; off <<= 1) {
        int t = __shfl_up(x, off, 64);
        if (lane >= off) x += t;
    }
    if (lane == 63) ws[w] = x;
    __syncthreads();
    int add = 0;
    for (int q = 0; q < w; ++q) add += ws[q];
    x += add;
    if (i < MM) partial[i] = x;
    if (tid == 255) bsum[blockIdx.x] = x;
}

__global__ void scanB_kernel(const int* __restrict__ bsum, int* __restrict__ boff) {
    int lane = threadIdx.x;  // 64 threads
    int carry = 0;
    for (int base = 0; base < NB; base += 64) {
        int v = (base + lane < NB) ? bsum[base + lane] : 0;
        int x = v;
        #pragma unroll
        for (int off = 1; off < 64; off <<= 1) {
            int t = __shfl_up(x, off, 64);
            if (lane >= off) x += t;
        }
        if (base + lane < NB) boff[base + lane] = carry + x - v;
        carry += __shfl(x, 63);
    }
}

__global__ void scanC_kernel(const int* __restrict__ partial, const int* __restrict__ cnt,
                             const int* __restrict__ boff, int* __restrict__ rowptr) {
    int i = blockIdx.x * 256 + threadIdx.x;
    if (i < MM) rowptr[i] = partial[i] - cnt[i] + boff[i >> 8];
    if (i == 0) rowptr[MM] = EE;
}

// --- bucket edges by row (atomic-free: pos = rowptr[r] + slot[e]) ---
__global__ void scatter_kernel(const int* __restrict__ row, const int* __restrict__ col,
                               const float* __restrict__ val, const float* __restrict__ dis,
                               const int* __restrict__ rowptr, const int* __restrict__ slot,
                               int* __restrict__ col_s, float* __restrict__ val_s) {
    int e = blockIdx.x * 256 + threadIdx.x;
    if (e < EE) {
        int r = row[e], c = col[e];
        int pos = rowptr[r] + slot[e];
        col_s[pos] = c;
        val_s[pos] = val[e] * dis[r] * dis[c];
    }
}

// --- X0b = bf16(features[index]) packed pairs: [MM][64] uints ---
__global__ void cvt_kernel(const float* __restrict__ feat, const int* __restrict__ index,
                           unsigned* __restrict__ X0b) {
    int i = blockIdx.x * 256 + threadIdx.x;
    if (i < MM * 64) {
        int node = i >> 6, k2 = i & 63;
        int idx = index[node];
        float2 f = ((const float2*)feat)[(size_t)idx * 64 + k2];
        X0b[i] = pk2(f.x, f.y);
    }
}

// --- SpMM on bf16 tables: 16-lane group per row, 4 groups/wave; 1 uint4 gather/edge ---
__global__ __launch_bounds__(256) void spmm_kernel(
    const int* __restrict__ rowptr, const int* __restrict__ cols,
    const float* __restrict__ vals, const unsigned short* __restrict__ X,
    unsigned short* __restrict__ Y) {
    int lane = threadIdx.x & 63;
    int wid = threadIdx.x >> 6;
    int g = lane >> 4, sub = lane & 15;
    int r = blockIdx.x * 16 + wid * 4 + g;
    bool valid = (r < MM);
    int rc = valid ? r : (MM - 1);
    int s = rowptr[rc], e = rowptr[rc + 1];
    const uint4* __restrict__ X4 = (const uint4*)X;
    float a[8] = {0.f, 0.f, 0.f, 0.f, 0.f, 0.f, 0.f, 0.f};
    for (int base = s; base < e; base += 16) {
        int cnt = min(16, e - base);
        int c = 0; float v = 0.f;
        if (sub < cnt) { c = cols[base + sub]; v = vals[base + sub]; }
        int j = 0;
        for (; j + 4 <= cnt; j += 4) {
            int c0 = __shfl(c, g * 16 + j);     float v0 = __shfl(v, g * 16 + j);
            int c1 = __shfl(c, g * 16 + j + 1); float v1 = __shfl(v, g * 16 + j + 1);
            int c2 = __shfl(c, g * 16 + j + 2); float v2 = __shfl(v, g * 16 + j + 2);
            int c3 = __shfl(c, g * 16 + j + 3); float v3 = __shfl(v, g * 16 + j + 3);
            uint4 u0 = X4[(size_t)c0 * 16 + sub];
            uint4 u1 = X4[(size_t)c1 * 16 + sub];
            uint4 u2 = X4[(size_t)c2 * 16 + sub];
            uint4 u3 = X4[(size_t)c3 * 16 + sub];
            fmab8(v0, u0, a);
            fmab8(v1, u1, a);
            fmab8(v2, u2, a);
            fmab8(v3, u3, a);
        }
        for (; j < cnt; ++j) {
            int cc = __shfl(c, g * 16 + j); float vv = __shfl(v, g * 16 + j);
            uint4 u0 = X4[(size_t)cc * 16 + sub];
            fmab8(vv, u0, a);
        }
    }
    if (valid) {
        uint4 o;
        o.x = pk2(a[0], a[1]); o.y = pk2(a[2], a[3]);
        o.z = pk2(a[4], a[5]); o.w = pk2(a[6], a[7]);
        ((uint4*)Y)[(size_t)r * 16 + sub] = o;
    }
}

// --- MFMA MLP head: 64 nodes/block, 4 waves, each wave = 16 nodes. ---
#define NPB 64
#define XSW 136   // x row stride in shorts (272B)
#define H1W 72    // h1/W2t row stride in shorts (144B)

__global__ __launch_bounds__(256) void mlp_kernel(
    const float* __restrict__ feat, const unsigned short* __restrict__ X3,
    const int* __restrict__ invidx,
    const float* __restrict__ W1, const float* __restrict__ b1,
    const float* __restrict__ W2, const float* __restrict__ b2,
    const float* __restrict__ W3, const float* __restrict__ b3,
    const float* __restrict__ W4, float* __restrict__ out) {
    __shared__ char smem[17408 + 17408 + 4608];   // 39424 B -> 4 blocks/CU
    short* xs  = (short*)smem;                    // [64][136] bf16 x rows
    short* h1s = (short*)smem;                    // overlay after L1: [64][72]
    short* w1t = (short*)(smem + 17408);          // [64 j][136] bf16 W1^T
    float* h2f = (float*)(smem + 17408);          // overlay after L2: [64][36] f32
    short* w2t = (short*)(smem + 17408 + 17408);  // [32 j][72] bf16 W2^T

    int tid = threadIdx.x;
    int nb = blockIdx.x * NPB;

    // stage x: 64 rows of 64 uints (bf16 pairs)
    #pragma unroll 4
    for (int it = 0; it < 16; ++it) {
        int i = it * 256 + tid;
        int node = i >> 6, u = i & 63;
        int n = nb + node;
        unsigned p = 0;
        if (n < NN) {
            int q = invidx[n];
            if (q >= 0) p = ((const unsigned*)X3)[(size_t)q * 64 + u];
            else { float2 f = ((const float2*)feat)[(size_t)n * 64 + u]; p = pk2(f.x, f.y); }
        }
        *((unsigned*)(xs + node * XSW) + u) = p;
    }
    // stage W1^T as bf16 pairs
    #pragma unroll 4
    for (int it = 0; it < 16; ++it) {
        int u = it * 256 + tid;
        int j = u & 63, kp = u >> 6;
        float w0 = W1[(2 * kp) * 64 + j], w1 = W1[(2 * kp + 1) * 64 + j];
        *((unsigned*)(w1t + j * XSW) + kp) = pk2(w0, w1);
    }
    // stage W2^T
    #pragma unroll
    for (int it = 0; it < 4; ++it) {
        int u = it * 256 + tid;
        int j = u & 31, kp = u >> 5;
        float w0 = W2[(2 * kp) * 32 + j], w1 = W2[(2 * kp + 1) * 32 + j];
        *((unsigned*)(w2t + j * H1W) + kp) = pk2(w0, w1);
    }
    __syncthreads();

    int lane = tid & 63, w = tid >> 6;
    int p = lane & 15, q = lane >> 4;

    // ---- L1: nodes w*16..w*16+15, all 64 outputs ----
    bf16x8 af[4];
    #pragma unroll
    for (int kc = 0; kc < 4; ++kc)
        af[kc] = *(const bf16x8*)(xs + (w * 16 + p) * XSW + kc * 32 + q * 8);

    f32x4 acc[4];
    #pragma unroll
    for (int jt = 0; jt < 4; ++jt) {
        float bv = b1[jt * 16 + p];
        acc[jt][0] = bv; acc[jt][1] = bv; acc[jt][2] = bv; acc[jt][3] = bv;
    }
    #pragma unroll
    for (int jt = 0; jt < 4; ++jt) {
        #pragma unroll
        for (int kc = 0; kc < 4; ++kc) {
            bf16x8 bf = *(const bf16x8*)(w1t + (jt * 16 + p) * XSW + kc * 32 + q * 8);
            acc[jt] = __builtin_amdgcn_mfma_f32_16x16x32_bf16(af[kc], bf, acc[jt], 0, 0, 0);
        }
    }
    __syncthreads();   // xs dead; safe to overlay h1
    #pragma unroll
    for (int jt = 0; jt < 4; ++jt) {
        #pragma unroll
        for (int r = 0; r < 4; ++r) {
            float v = acc[jt][r];
            v = v > 0.f ? v : 0.01f * v;
            h1s[(w * 16 + q * 4 + r) * H1W + jt * 16 + p] = (short)rne(v);
        }
    }
    __syncthreads();

    // ---- L2 ----
    bf16x8 a2f[2];
    #pragma unroll
    for (int kc = 0; kc < 2; ++kc)
        a2f[kc] = *(const bf16x8*)(h1s + (w * 16 + p) * H1W + kc * 32 + q * 8);
    f32x4 acc2[2];
    #pragma unroll
    for (int jt = 0; jt < 2; ++jt) {
        float bv = b2[jt * 16 + p];
        acc2[jt][0] = bv; acc2[jt][1] = bv; acc2[jt][2] = bv; acc2[jt][3] = bv;
        #pragma unroll
        for (int kc = 0; kc < 2; ++kc) {
            bf16x8 bf = *(const bf16x8*)(w2t + (jt * 16 + p) * H1W + kc * 32 + q * 8);
            acc2[jt] = __builtin_amdgcn_mfma_f32_16x16x32_bf16(a2f[kc], bf, acc2[jt], 0, 0, 0);
        }
    }
    __syncthreads();   // w1t dead; safe to overlay h2f
    #pragma unroll
    for (int jt = 0; jt < 2; ++jt) {
        #pragma unroll
        for (int r = 0; r < 4; ++r) {
            float v = acc2[jt][r];
            v = v > 0.f ? v : 0.01f * v;
            h2f[(w * 16 + q * 4 + r) * 36 + jt * 16 + p] = v;
        }
    }
    __syncthreads();

    // ---- L3+L4 scalar tail ----
    int node = w * 16 + p;
    float a3[21];
    #pragma unroll
    for (int j = 0; j < 21; ++j) a3[j] = b3[j];
    #pragma unroll 4
    for (int k = 0; k < 32; ++k) {
        float hk = h2f[node * 36 + k];
        fma21(hk, W3 + k * 21, a3);
    }
    float s = 0.f;
    #pragma unroll
    for (int j = 0; j < 21; ++j) {
        float vj = a3[j] > 0.f ? a3[j] : 0.01f * a3[j];
        s = fmaf(vj, W4[j], s);
    }
    if (q == 0) {
        int n = nb + node;
        if (n < NN) out[n] = 1.f / (1.f + expf(-s));
    }
}

extern "C" void kernel_launch(void* const* d_in, const int* in_sizes, int n_in,
                              void* d_out, int out_size, void* d_ws, size_t ws_size,
                              hipStream_t stream) {
    const float* feat = (const float*)d_in[0];
    const int*   index = (const int*)d_in[1];
    const int*   erow = (const int*)d_in[2];
    const int*   ecol = (const int*)d_in[3];
    const float* evalp = (const float*)d_in[4];
    const float* W1 = (const float*)d_in[5];
    const float* b1 = (const float*)d_in[6];
    const float* W2 = (const float*)d_in[7];
    const float* b2 = (const float*)d_in[8];
    const float* W3 = (const float*)d_in[9];
    const float* b3 = (const float*)d_in[10];
    const float* W4 = (const float*)d_in[11];
    float* out = (float*)d_out;

    char* ws = (char*)d_ws;
    size_t off = 0;
    auto alloc = [&](size_t bytes) -> void* {
        void* p = ws + off;
        off += (bytes + 255) & ~(size_t)255;
        return p;
    };
    unsigned long long* dcpack = (unsigned long long*)alloc((size_t)MM * 8);
    float* dis     = (float*)alloc((size_t)MM * 4);
    int*   cnt     = (int*)  alloc((size_t)MM * 4);
    int*   rowptr  = (int*)  alloc((size_t)(MM + 1) * 4);
    int*   partial = (int*)  alloc((size_t)MM * 4);
    int*   bsum    = (int*)  alloc((size_t)NB * 4);
    int*   boff    = (int*)  alloc((size_t)NB * 4);
    int*   slot    = (int*)  alloc((size_t)EE * 4);
    int*   col_s   = (int*)  alloc((size_t)EE * 4);
    float* val_s   = (float*)alloc((size_t)EE * 4);
    int*   invidx  = (int*)  alloc((size_t)NN * 4);
    unsigned*       X0b = (unsigned*)      alloc((size_t)MM * DD * 2);
    unsigned short* Xa  = (unsigned short*)alloc((size_t)MM * DD * 2);
    unsigned short* Xb  = (unsigned short*)alloc((size_t)MM * DD * 2);

    hipMemsetAsync(dcpack, 0, (size_t)MM * 8, stream);

    deg_count_kernel<<<(EE + 255) / 256, 256, 0, stream>>>(erow, evalp, dcpack, slot, invidx);
    fused_setup_kernel<<<NB, 256, 0, stream>>>(dcpack, dis, index, invidx, cnt, partial, bsum);
    scanB_kernel<<<1, 64, 0, stream>>>(bsum, boff);
    scanC_kernel<<<(MM + 255) / 256, 256, 0, stream>>>(partial, cnt, boff, rowptr);
    scatter_kernel<<<(EE + 255) / 256, 256, 0, stream>>>(erow, ecol, evalp, dis,
                                                         rowptr, slot, col_s, val_s);
    cvt_kernel<<<(MM * 64 + 255) / 256, 256, 0, stream>>>(feat, index, X0b);

    spmm_kernel<<<(MM + 15) / 16, 256, 0, stream>>>(rowptr, col_s, val_s,
                                                    (const unsigned short*)X0b, Xa);
    spmm_kernel<<<(MM + 15) / 16, 256, 0, stream>>>(rowptr, col_s, val_s, Xa, Xb);
    spmm_kernel<<<(MM + 15) / 16, 256, 0, stream>>>(rowptr, col_s, val_s, Xb, Xa);

    mlp_kernel<<<(NN + NPB - 1) / NPB, 256, 0, stream>>>(feat, Xa, invidx,
                                                         W1, b1, W2, b2, W3, b3, W4, out);
}